// Round 3
// baseline (1002.767 us; speedup 1.0000x reference)
//
#include <hip/hip_runtime.h>

typedef unsigned short u16;
typedef __attribute__((ext_vector_type(8))) _Float16 f16x8;
typedef __attribute__((ext_vector_type(4))) float f32x4;
typedef __attribute__((ext_vector_type(4))) unsigned short u16x4;
typedef __attribute__((ext_vector_type(8))) unsigned short u16x8;

#define MFMA16F __builtin_amdgcn_mfma_f32_16x16x32_f16

#define HW   16384
#define NCLS 150
#define NPAD 160
#define CDIM 256
#define NCH  64      // chunks per batch
#define CHPX 256     // pixels per chunk
#define NSUB 4       // 64-px subtiles per chunk

// LDS strides (shorts). byte stride % 16 == 0 (b128-aligned), % 128 != 0 (bank spread)
#define FT_STRIDE 264   // featT [64 px][256 c]   -> 528 B rows
#define FN_STRIDE 72    // featN [256 c][64 px]   -> 144 B rows
#define U_STRIDE  72    // U     [160 n][64 px]   -> 144 B rows
#define W_STRIDE  168   // w     [64 px][160 n]   -> 336 B rows

// K3 LDS layout (bytes)
#define L_FT   0        // 33792; U (23040) and w (21504) alias here after S-GEMM
#define L_FN   33792    // 36864
#define L_ROWM 70656    // [160][4] f32 = 2560 (row max -> fac2)
#define L_ROWS 73216    // [160][4] f32 = 2560 (row sums)
#define L_POSM 75776    // [2][64] f32
#define L_POSS 76288    // [2][64] f32
#define L_MPV  76800    // [64] f32
#define L_RZP  77056    // [64] f32
#define L_MRUN 77312    // [160] f32
#define L_LRUN 77952    // [160] f32
#define L_FFAC 78592    // [160] f32
#define K3_LDS 79232    // -> 2 blocks/CU (158464 <= 163840)

// workspace offsets (bytes)
#define WS_CLSF  0          // [8][160][256] f16
#define WS_CLSWT 655360     // [8][256][160] f16
#define WS_MS    1310720    // [8][64][160] f32
#define WS_LS    1638400
#define WS_WCH   1966080
#define WS_PART  2293760    // [8][64][256][160] f16 = 41,943,040

__device__ __forceinline__ u16 f2h(float f){
  return __builtin_bit_cast(u16, (_Float16)f);
}
__device__ __forceinline__ float h2f(u16 h){
  return (float)__builtin_bit_cast(_Float16, h);
}

// ---------------- K0: cls -> f16 (padded to 160 rows), cls_wT = (cls @ W_f^T)^T in f16
__global__ __launch_bounds__(256) void k0(const float* __restrict__ cls, const float* __restrict__ Wf,
                                          u16* __restrict__ clsF, u16* __restrict__ clsWT){
  int b = blockIdx.x / NPAD, n = blockIdx.x % NPAD, t = threadIdx.x;
  __shared__ float row[256];
  int bn = b*NPAD + n;
  if (n < NCLS){
    float v = cls[(b*NCLS + n)*CDIM + t];
    clsF[bn*CDIM + t] = f2h(v);
    row[t] = v;
    __syncthreads();
    float acc = 0.f;
    const float* wr = Wf + t*CDIM;
    #pragma unroll 4
    for (int c = 0; c < 256; c += 4){
      acc += row[c]*wr[c] + row[c+1]*wr[c+1] + row[c+2]*wr[c+2] + row[c+3]*wr[c+3];
    }
    clsWT[(b*CDIM + t)*NPAD + n] = f2h(acc);
  } else {
    clsF[bn*CDIM + t] = 0;
    clsWT[(b*CDIM + t)*NPAD + n] = 0;
  }
}

// ---------------- K3: single-pass fused kernel, S in registers, 2 blocks/CU
__global__ __launch_bounds__(512, 4) void k3(const float* __restrict__ feat,
                                             const u16* __restrict__ clsF,
                                             const u16* __restrict__ clsWT,
                                             u16* __restrict__ part,
                                             float* __restrict__ mS, float* __restrict__ lS,
                                             float* __restrict__ out1){
  extern __shared__ char sm[];
  u16*  ftF  = (u16*)(sm + L_FT);
  u16*  U    = (u16*)(sm + L_FT);     // alias (after S-GEMM)
  u16*  wls  = (u16*)(sm + L_FT);     // alias (after P4)
  u16*  fN   = (u16*)(sm + L_FN);
  float* rowM  = (float*)(sm + L_ROWM);
  float* rowS  = (float*)(sm + L_ROWS);
  float* posm  = (float*)(sm + L_POSM);
  float* poss  = (float*)(sm + L_POSS);
  float* mpv   = (float*)(sm + L_MPV);
  float* rzp   = (float*)(sm + L_RZP);
  float* m_run = (float*)(sm + L_MRUN);
  float* l_run = (float*)(sm + L_LRUN);
  float* ffac  = (float*)(sm + L_FFAC);

  int b = blockIdx.x & 7, ch = blockIdx.x >> 3, t = threadIdx.x;
  const float* featG = feat + (size_t)b*(CDIM*HW);
  const u16* clsB  = clsF  + b*NPAD*CDIM;
  const u16* clsWB = clsWT + b*CDIM*NPAD;

  int lane = t & 63, wv = t >> 6;
  int l15 = lane & 15, lk = (lane >> 4) & 3;
  int nh = wv >> 2, pq = wv & 3;
  int nbase = nh*80;
  int col = pq*16 + l15;
  int cstrip = wv*32;

  if (t < NPAD){ m_run[t] = -3.0e38f; l_run[t] = 0.f; }

  f32x4 accC[2][10];
  #pragma unroll
  for (int f = 0; f < 2; ++f)
    #pragma unroll
    for (int nf = 0; nf < 10; ++nf) accC[f][nf] = (f32x4){0.f, 0.f, 0.f, 0.f};
  __syncthreads();

  for (int sub = 0; sub < NSUB; ++sub){
    int p0 = ch*CHPX + sub*64;
    // ---- stage: featT f16 [p][c] + featN f16 [c][p]
    {
      int p = t & 63, cg = t >> 6;
      #pragma unroll
      for (int i = 0; i < 8; ++i){
        int c0 = (i*8 + cg)*4;
        const float* g0 = featG + (size_t)c0*HW + p0 + p;
        float v0 = g0[0];
        float v1 = g0[HW];
        float v2 = g0[2*HW];
        float v3 = g0[3*HW];
        u16 h0 = f2h(v0), h1 = f2h(v1), h2 = f2h(v2), h3 = f2h(v3);
        u16x4 hv = {h0, h1, h2, h3};
        *(u16x4*)&ftF[p*FT_STRIDE + c0] = hv;
        fN[(c0+0)*FN_STRIDE + p] = h0;
        fN[(c0+1)*FN_STRIDE + p] = h1;
        fN[(c0+2)*FN_STRIDE + p] = h2;
        fN[(c0+3)*FN_STRIDE + p] = h3;
      }
    }
    __syncthreads();   // B1

    // ---- S-GEMM into registers: acc[f][r] = S[nbase+16f+4lk+r][col]
    f32x4 acc[5];
    #pragma unroll
    for (int f = 0; f < 5; ++f) acc[f] = (f32x4){0.f, 0.f, 0.f, 0.f};
    #pragma unroll
    for (int kb = 0; kb < 8; ++kb){
      int ko = kb*32 + lk*8;
      f16x8 bh = *(const f16x8*)&ftF[(pq*16 + l15)*FT_STRIDE + ko];
      #pragma unroll
      for (int f = 0; f < 5; ++f){
        f16x8 ah = *(const f16x8*)&clsB[(nbase + f*16 + l15)*CDIM + ko];
        acc[f] = MFMA16F(ah, bh, acc[f], 0, 0, 0);
      }
    }

    // ---- in-register stats
    // pos (per-pixel) max over valid n, reduce over (f,r) in-lane then lk via xor16/32
    {
      float pmax = -3.0e38f;
      #pragma unroll
      for (int f = 0; f < 5; ++f)
        #pragma unroll
        for (int r = 0; r < 4; ++r){
          int rowi = nbase + 16*f + 4*lk + r;
          if (rowi < NCLS) pmax = fmaxf(pmax, acc[f][r]);
        }
      pmax = fmaxf(pmax, __shfl_xor(pmax, 16));
      pmax = fmaxf(pmax, __shfl_xor(pmax, 32));
      if (lk == 0) posm[nh*64 + col] = pmax;
    }
    // cls (per-row) max+sum over the wave's 16 cols; e_loc overwrites acc
    #pragma unroll
    for (int f = 0; f < 5; ++f){
      #pragma unroll
      for (int r = 0; r < 4; ++r){
        float v = acc[f][r];
        float m = v;
        m = fmaxf(m, __shfl_xor(m, 1));
        m = fmaxf(m, __shfl_xor(m, 2));
        m = fmaxf(m, __shfl_xor(m, 4));
        m = fmaxf(m, __shfl_xor(m, 8));
        float el = __expf(v - m);
        float s = el;
        s += __shfl_xor(s, 1);
        s += __shfl_xor(s, 2);
        s += __shfl_xor(s, 4);
        s += __shfl_xor(s, 8);
        acc[f][r] = el;
        if (l15 == f){
          int rowi = nbase + 16*f + 4*lk + r;
          rowM[rowi*4 + pq] = m;
          rowS[rowi*4 + pq] = s;
        }
      }
    }
    __syncthreads();   // B2

    // ---- combine1: cls running stats (t<160) + pos max combine (last wave)
    if (t < NPAD){
      int n = t;
      float m_old = m_run[n];
      float rm0 = rowM[n*4+0], rm1 = rowM[n*4+1], rm2 = rowM[n*4+2], rm3 = rowM[n*4+3];
      float m_loc = fmaxf(fmaxf(rm0, rm1), fmaxf(rm2, rm3));
      float m_new = fmaxf(m_old, m_loc);
      float ff = __expf(m_old - m_new);
      float f0 = __expf(rm0 - m_new), f1 = __expf(rm1 - m_new);
      float f2 = __expf(rm2 - m_new), f3 = __expf(rm3 - m_new);
      float ls = rowS[n*4+0]*f0 + rowS[n*4+1]*f1 + rowS[n*4+2]*f2 + rowS[n*4+3]*f3;
      l_run[n] = l_run[n]*ff + ls;
      m_run[n] = m_new;
      ffac[n] = ff;
      rowM[n*4+0] = f0; rowM[n*4+1] = f1; rowM[n*4+2] = f2; rowM[n*4+3] = f3;  // fac2
    }
    if (t >= 448){
      int p = t - 448;
      mpv[p] = fmaxf(posm[p], posm[64 + p]);
    }
    __syncthreads();   // B3

    // ---- U-phase: e = e_loc*fac2 -> U tile; pos-sum partials; accC rescale
    {
      float mpc = mpv[col];
      float s = 0.f;
      #pragma unroll
      for (int f = 0; f < 5; ++f){
        #pragma unroll
        for (int r = 0; r < 4; ++r){
          int rowi = nbase + 16*f + 4*lk + r;
          float e = acc[f][r] * rowM[rowi*4 + pq];
          acc[f][r] = e;
          U[rowi*U_STRIDE + col] = f2h(e);
          if (rowi < NCLS) s += e * __expf(m_run[rowi] - mpc);
        }
      }
      s += __shfl_xor(s, 16);
      s += __shfl_xor(s, 32);
      if (lk == 0) poss[nh*64 + col] = s;
    }
    #pragma unroll
    for (int nf = 0; nf < 10; ++nf){
      float ff = ffac[nf*16 + l15];
      #pragma unroll
      for (int f = 0; f < 2; ++f){
        accC[f][nf][0] *= ff; accC[f][nf][1] *= ff;
        accC[f][nf][2] *= ff; accC[f][nf][3] *= ff;
      }
    }
    __syncthreads();   // B4

    if (t < 64) rzp[t] = 1.0f / (poss[t] + poss[64 + t]);
    __syncthreads();   // B5

    // ---- P4: accC[c][n] += featN[c][p] * U[n][p]
    #pragma unroll
    for (int kb = 0; kb < 2; ++kb){
      int ko = kb*32 + lk*8;
      f16x8 a0 = *(const f16x8*)&fN[(cstrip + l15)*FN_STRIDE + ko];
      f16x8 a1 = *(const f16x8*)&fN[(cstrip + 16 + l15)*FN_STRIDE + ko];
      #pragma unroll
      for (int nf = 0; nf < 10; ++nf){
        f16x8 bb = *(const f16x8*)&U[(nf*16 + l15)*U_STRIDE + ko];
        accC[0][nf] = MFMA16F(a0, bb, accC[0][nf], 0, 0, 0);
        accC[1][nf] = MFMA16F(a1, bb, accC[1][nf], 0, 0, 0);
      }
    }
    __syncthreads();   // B6 (U dead)

    // ---- w-phase: w[p][n] = exp(S - mp)/Zp (0 for pad n)
    {
      float mpc = mpv[col];
      float rz = rzp[col];
      #pragma unroll
      for (int f = 0; f < 5; ++f){
        #pragma unroll
        for (int r = 0; r < 4; ++r){
          int rowi = nbase + 16*f + 4*lk + r;
          float wv_ = (rowi < NCLS) ? acc[f][r] * __expf(m_run[rowi] - mpc) * rz : 0.f;
          wls[col*W_STRIDE + rowi] = f2h(wv_);
        }
      }
    }
    __syncthreads();   // B7

    // ---- P5: accO[c][p] = sum_n clsWT[c][n]*w[p][n]; epilogue += feat -> out1
    {
      f32x4 accO[2][4];
      #pragma unroll
      for (int f = 0; f < 2; ++f)
        #pragma unroll
        for (int pf = 0; pf < 4; ++pf) accO[f][pf] = (f32x4){0.f, 0.f, 0.f, 0.f};
      #pragma unroll
      for (int kb = 0; kb < 5; ++kb){
        int ko = kb*32 + lk*8;
        f16x8 a0 = *(const f16x8*)&clsWB[(cstrip + l15)*NPAD + ko];
        f16x8 a1 = *(const f16x8*)&clsWB[(cstrip + 16 + l15)*NPAD + ko];
        #pragma unroll
        for (int pf = 0; pf < 4; ++pf){
          f16x8 bb = *(const f16x8*)&wls[(pf*16 + l15)*W_STRIDE + ko];
          accO[0][pf] = MFMA16F(a0, bb, accO[0][pf], 0, 0, 0);
          accO[1][pf] = MFMA16F(a1, bb, accO[1][pf], 0, 0, 0);
        }
      }
      #pragma unroll
      for (int f = 0; f < 2; ++f){
        #pragma unroll
        for (int r = 0; r < 4; ++r){
          int c = cstrip + f*16 + lk*4 + r;
          float* ob = out1 + (size_t)(b*CDIM + c)*HW + p0;
          #pragma unroll
          for (int pf = 0; pf < 4; ++pf){
            int pp = pf*16 + l15;
            ob[pp] = accO[f][pf][r] + h2f(fN[c*FN_STRIDE + pp]);
          }
        }
      }
    }
    __syncthreads();   // B8
  }

  // ---- dump per-chunk partials (f16) + chunk stats
  #pragma unroll
  for (int f = 0; f < 2; ++f){
    #pragma unroll
    for (int nf = 0; nf < 10; ++nf){
      #pragma unroll
      for (int r = 0; r < 4; ++r){
        int c = cstrip + f*16 + lk*4 + r;
        int n = nf*16 + l15;
        part[((size_t)(b*NCH + ch)*CDIM + c)*NPAD + n] = f2h(accC[f][nf][r]);
      }
    }
  }
  if (t < NPAD){
    mS[(b*NCH + ch)*NPAD + t] = m_run[t];
    lS[(b*NCH + ch)*NPAD + t] = l_run[t];
  }
}

// ---------------- K2p: per-chunk cls-softmax weights e^{m_ch-m_g}/Z
__global__ __launch_bounds__(256) void k2p(const float* __restrict__ mS, const float* __restrict__ lS,
                                           float* __restrict__ wch){
  int b = blockIdx.x, t = threadIdx.x;
  if (t < NPAD){
    float m = -3.0e38f;
    for (int s = 0; s < NCH; ++s) m = fmaxf(m, mS[(b*NCH+s)*NPAD + t]);
    float Z = 0.f;
    for (int s = 0; s < NCH; ++s) Z += lS[(b*NCH+s)*NPAD + t] * __expf(mS[(b*NCH+s)*NPAD + t] - m);
    float rZ = 1.0f / Z;
    for (int s = 0; s < NCH; ++s) wch[(b*NCH+s)*NPAD + t] = __expf(mS[(b*NCH+s)*NPAD + t] - m) * rZ;
  }
}

// ---------------- K4: weighted sum of chunk partials, project with W_cls, add cls_repr -> out0
__global__ __launch_bounds__(256) void k4(const u16* __restrict__ part, const float* __restrict__ wch,
                                          const float* __restrict__ Wc,
                                          const float* __restrict__ cls, float* __restrict__ out0){
  int b = blockIdx.x / 10, nb = blockIdx.x % 10, t = threadIdx.x;
  __shared__ float comb[256][17];
  __shared__ float wt[NCH][16];
  #pragma unroll
  for (int q = 0; q < 4; ++q){
    int idx = t + q*256;
    int s = idx >> 4, j = idx & 15;
    wt[s][j] = wch[(b*NCH + s)*NPAD + nb*16 + j];
  }
  __syncthreads();
  float a16[16];
  #pragma unroll
  for (int j = 0; j < 16; ++j) a16[j] = 0.f;
  for (int s = 0; s < NCH; ++s){
    const u16* src = part + (size_t)((b*NCH+s)*CDIM + t)*NPAD + nb*16;
    u16x8 v0 = *(const u16x8*)&src[0];
    u16x8 v1 = *(const u16x8*)&src[8];
    #pragma unroll
    for (int j = 0; j < 8; ++j) a16[j] += h2f(v0[j]) * wt[s][j];
    #pragma unroll
    for (int j = 0; j < 8; ++j) a16[8+j] += h2f(v1[j]) * wt[s][8+j];
  }
  #pragma unroll
  for (int j = 0; j < 16; ++j) comb[t][j] = a16[j];
  __syncthreads();
  const float* wr = Wc + t*CDIM;
  for (int j = 0; j < 16; ++j){
    int n = nb*16 + j;
    if (n >= NCLS) break;
    float o = 0.f;
    #pragma unroll 4
    for (int c = 0; c < 256; c += 4){
      o += comb[c][j]*wr[c] + comb[c+1][j]*wr[c+1] + comb[c+2][j]*wr[c+2] + comb[c+3][j]*wr[c+3];
    }
    out0[(b*NCLS + n)*CDIM + t] = cls[(b*NCLS + n)*CDIM + t] + o;
  }
}

extern "C" void kernel_launch(void* const* d_in, const int* in_sizes, int n_in,
                              void* d_out, int out_size, void* d_ws, size_t ws_size,
                              hipStream_t stream){
  (void)in_sizes; (void)n_in; (void)out_size; (void)ws_size;
  const float* cls  = (const float*)d_in[0];   // [8][150][256]
  const float* feat = (const float*)d_in[1];   // [8][256][16384]
  const float* Wc   = (const float*)d_in[2];   // [256][256]
  const float* Wf   = (const float*)d_in[3];   // [256][256]
  float* out0 = (float*)d_out;                 // [8][150][256]
  float* out1 = out0 + 8*NCLS*CDIM;            // [8][256][16384]
  char* ws = (char*)d_ws;
  u16*  clsF  = (u16*)(ws + WS_CLSF);
  u16*  clsWT = (u16*)(ws + WS_CLSWT);
  float* mSv  = (float*)(ws + WS_MS);
  float* lSv  = (float*)(ws + WS_LS);
  float* wchv = (float*)(ws + WS_WCH);
  u16*  part  = (u16*)(ws + WS_PART);

  hipFuncSetAttribute((const void*)k3, hipFuncAttributeMaxDynamicSharedMemorySize, K3_LDS);

  k0<<<8*NPAD, 256, 0, stream>>>(cls, Wf, clsF, clsWT);
  k3<<<8*NCH, 512, K3_LDS, stream>>>(feat, clsF, clsWT, part, mSv, lSv, out1);
  k2p<<<8, 256, 0, stream>>>(mSv, lSv, wchv);
  k4<<<80, 256, 0, stream>>>(part, wchv, Wc, cls, out0);
}

// Round 4
// 668.800 us; speedup vs baseline: 1.4994x; 1.4994x over previous
//
#include <hip/hip_runtime.h>

typedef unsigned short u16;
typedef __attribute__((ext_vector_type(8))) _Float16 f16x8;
typedef __attribute__((ext_vector_type(4))) float f32x4;
typedef __attribute__((ext_vector_type(4))) unsigned short u16x4;
typedef __attribute__((ext_vector_type(8))) unsigned short u16x8;

#define MFMA16F __builtin_amdgcn_mfma_f32_16x16x32_f16

#define HW   16384
#define NCLS 150
#define NPAD 160
#define CDIM 256
#define NSV  256     // 64-px subtiles per batch

// LDS strides (shorts). byte stride % 16 == 0 (b128-aligned), % 128 != 0 (bank spread)
#define FT_STRIDE 264   // featT [64 px][256 c]
#define FN_STRIDE 72    // featN [256 c][64 px]
#define U_STRIDE  72    // U     [160 n][64 px]
#define W_STRIDE  168   // w     [64 px][160 n]

// kA LDS layout (bytes)
#define A_FT    0        // 33792; U tile (23040) then w tile (21504) alias here
#define A_FN    33792    // 36864
#define A_ROWM  70656    // [160][4] f32
#define A_ROWS  73216    // [160][4] f32
#define A_ROWMF 75776    // [160] f32
#define A_POSM  76416    // [2][64] f32
#define A_POSS  76928    // [2][64] f32
#define A_MPV   77440    // [64] f32
#define A_RZP   77696    // [64] f32
#define A_LDS   77952    // 2 blocks/CU

// kC LDS layout (bytes)
#define C_U    0         // [160][U_STRIDE] f16 = 23040
#define C_FN   23040     // [256][FN_STRIDE] f16 = 36864
#define C_LDS  59904     // 2 blocks/CU

// workspace offsets (bytes)
#define WS_CLSF  0           // [8][160][256] f16
#define WS_CLSWT 655360      // [8][256][160] f16
#define WS_MS    1310720     // [8][256][160] f32
#define WS_LS    2621440     // [8][256][160] f32
#define WS_WCH   3932160     // [8][256][160] f32
#define WS_U     5242880     // [8][256][160][64] f16 = 41,943,040
#define WS_PART  47185920    // [8][64][256][160] f16 = 20,971,520  (total 68,157,440)

__device__ __forceinline__ u16 f2h(float f){
  return __builtin_bit_cast(u16, (_Float16)f);
}
__device__ __forceinline__ float h2f(u16 h){
  return (float)__builtin_bit_cast(_Float16, h);
}

// ---------------- K0: cls -> f16 (padded to 160 rows), cls_wT = (cls @ W_f^T)^T in f16
__global__ __launch_bounds__(256) void k0(const float* __restrict__ cls, const float* __restrict__ Wf,
                                          u16* __restrict__ clsF, u16* __restrict__ clsWT){
  int b = blockIdx.x / NPAD, n = blockIdx.x % NPAD, t = threadIdx.x;
  __shared__ float row[256];
  int bn = b*NPAD + n;
  if (n < NCLS){
    float v = cls[(b*NCLS + n)*CDIM + t];
    clsF[bn*CDIM + t] = f2h(v);
    row[t] = v;
    __syncthreads();
    float acc = 0.f;
    const float* wr = Wf + t*CDIM;
    #pragma unroll 4
    for (int c = 0; c < 256; c += 4){
      acc += row[c]*wr[c] + row[c+1]*wr[c+1] + row[c+2]*wr[c+2] + row[c+3]*wr[c+3];
    }
    clsWT[(b*CDIM + t)*NPAD + n] = f2h(acc);
  } else {
    clsF[bn*CDIM + t] = 0;
    clsWT[(b*CDIM + t)*NPAD + n] = 0;
  }
}

// ---------------- kA: pos direction (out1) + U tiles + per-subtile cls stats
__global__ __launch_bounds__(512, 4) void kA(const float* __restrict__ feat,
                                             const u16* __restrict__ clsF,
                                             const u16* __restrict__ clsWT,
                                             u16* __restrict__ Ug,
                                             float* __restrict__ mS, float* __restrict__ lS,
                                             float* __restrict__ out1){
  extern __shared__ char sm[];
  u16*  ftF = (u16*)(sm + A_FT);
  u16*  Ul  = (u16*)(sm + A_FT);     // alias after S-GEMM
  u16*  wls = (u16*)(sm + A_FT);     // alias after U dump
  u16*  fN  = (u16*)(sm + A_FN);
  float* rowM  = (float*)(sm + A_ROWM);
  float* rowS  = (float*)(sm + A_ROWS);
  float* rowMf = (float*)(sm + A_ROWMF);
  float* posm  = (float*)(sm + A_POSM);
  float* poss  = (float*)(sm + A_POSS);
  float* mpv   = (float*)(sm + A_MPV);
  float* rzp   = (float*)(sm + A_RZP);

  int b = blockIdx.x & 7, blk = blockIdx.x >> 3, t = threadIdx.x;
  const float* featG = feat + (size_t)b*(CDIM*HW);
  const u16* clsB  = clsF  + b*NPAD*CDIM;
  const u16* clsWB = clsWT + b*CDIM*NPAD;

  int lane = t & 63, wvi = t >> 6;
  int l15 = lane & 15, lk = (lane >> 4) & 3;
  int nh = wvi >> 2, pq = wvi & 3;
  int nbase = nh*80;
  int col = pq*16 + l15;
  int cstrip = wvi*32;

  for (int sub = 0; sub < 4; ++sub){
    int sv = blk*4 + sub;
    int p0 = sv*64;
    // ---- stage featT [p][c] + featN [c][p] (f16)
    {
      int p = t & 63, cg = t >> 6;
      #pragma unroll
      for (int i = 0; i < 8; ++i){
        int c0 = (i*8 + cg)*4;
        const float* g0 = featG + (size_t)c0*HW + p0 + p;
        float v0 = g0[0];
        float v1 = g0[HW];
        float v2 = g0[2*HW];
        float v3 = g0[3*HW];
        u16 h0 = f2h(v0), h1 = f2h(v1), h2 = f2h(v2), h3 = f2h(v3);
        u16x4 hv = {h0, h1, h2, h3};
        *(u16x4*)&ftF[p*FT_STRIDE + c0] = hv;
        fN[(c0+0)*FN_STRIDE + p] = h0;
        fN[(c0+1)*FN_STRIDE + p] = h1;
        fN[(c0+2)*FN_STRIDE + p] = h2;
        fN[(c0+3)*FN_STRIDE + p] = h3;
      }
    }
    __syncthreads();   // B1

    // ---- S-GEMM into registers: acc[f][r] = S[nbase+16f+4lk+r][col]  (kept as S)
    f32x4 acc[5];
    #pragma unroll
    for (int f = 0; f < 5; ++f) acc[f] = (f32x4){0.f, 0.f, 0.f, 0.f};
    #pragma unroll
    for (int kb = 0; kb < 8; ++kb){
      int ko = kb*32 + lk*8;
      f16x8 bh = *(const f16x8*)&ftF[(pq*16 + l15)*FT_STRIDE + ko];
      #pragma unroll
      for (int f = 0; f < 5; ++f){
        f16x8 ah = *(const f16x8*)&clsB[(nbase + f*16 + l15)*CDIM + ko];
        acc[f] = MFMA16F(ah, bh, acc[f], 0, 0, 0);
      }
    }

    // ---- wave-local row (cls) stats: m,l over this wave's 16 cols
    #pragma unroll
    for (int f = 0; f < 5; ++f){
      #pragma unroll
      for (int r = 0; r < 4; ++r){
        float v = acc[f][r];
        float m = v;
        m = fmaxf(m, __shfl_xor(m, 1));
        m = fmaxf(m, __shfl_xor(m, 2));
        m = fmaxf(m, __shfl_xor(m, 4));
        m = fmaxf(m, __shfl_xor(m, 8));
        float s = __expf(v - m);
        s += __shfl_xor(s, 1);
        s += __shfl_xor(s, 2);
        s += __shfl_xor(s, 4);
        s += __shfl_xor(s, 8);
        if (l15 == f){
          int rowi = nbase + 16*f + 4*lk + r;
          rowM[rowi*4 + pq] = m;
          rowS[rowi*4 + pq] = s;
        }
      }
    }
    // ---- pos (per-pixel) max over valid n
    {
      float pmax = -3.0e38f;
      #pragma unroll
      for (int f = 0; f < 5; ++f)
        #pragma unroll
        for (int r = 0; r < 4; ++r){
          int rowi = nbase + 16*f + 4*lk + r;
          if (rowi < NCLS) pmax = fmaxf(pmax, acc[f][r]);
        }
      pmax = fmaxf(pmax, __shfl_xor(pmax, 16));
      pmax = fmaxf(pmax, __shfl_xor(pmax, 32));
      if (lk == 0) posm[nh*64 + col] = pmax;
    }
    __syncthreads();   // B2

    // ---- combine: per-subtile cls stats -> global; pos max combine
    if (t < NPAD){
      float rm0 = rowM[t*4+0], rm1 = rowM[t*4+1], rm2 = rowM[t*4+2], rm3 = rowM[t*4+3];
      float msub = fmaxf(fmaxf(rm0, rm1), fmaxf(rm2, rm3));
      float l = rowS[t*4+0]*__expf(rm0 - msub) + rowS[t*4+1]*__expf(rm1 - msub)
              + rowS[t*4+2]*__expf(rm2 - msub) + rowS[t*4+3]*__expf(rm3 - msub);
      rowMf[t] = msub;
      mS[(size_t)(b*NSV + sv)*NPAD + t] = msub;
      lS[(size_t)(b*NSV + sv)*NPAD + t] = l;
    }
    if (t >= 448){
      int p = t - 448;
      mpv[p] = fmaxf(posm[p], posm[64 + p]);
    }
    __syncthreads();   // B3

    // ---- U tile (ftF alias): U[n][p] = exp(S - m_sub[n]); pos-sum partials
    {
      float mpc = mpv[col];
      float s = 0.f;
      #pragma unroll
      for (int f = 0; f < 5; ++f){
        #pragma unroll
        for (int r = 0; r < 4; ++r){
          int rowi = nbase + 16*f + 4*lk + r;
          Ul[rowi*U_STRIDE + col] = f2h(__expf(acc[f][r] - rowMf[rowi]));
          if (rowi < NCLS) s += __expf(acc[f][r] - mpc);
        }
      }
      s += __shfl_xor(s, 16);
      s += __shfl_xor(s, 32);
      if (lk == 0) poss[nh*64 + col] = s;
    }
    __syncthreads();   // B4

    // ---- dump U tile to global (coalesced 64-B chunks); rzp
    if (t < 320){
      int n = t >> 1, half = t & 1;
      const u16* srcL = &Ul[n*U_STRIDE + half*32];
      u16x8 d0 = *(const u16x8*)&srcL[0];
      u16x8 d1 = *(const u16x8*)&srcL[8];
      u16x8 d2 = *(const u16x8*)&srcL[16];
      u16x8 d3 = *(const u16x8*)&srcL[24];
      u16* dst = Ug + ((size_t)(b*NSV + sv)*NPAD + n)*64 + half*32;
      *(u16x8*)&dst[0]  = d0;
      *(u16x8*)&dst[8]  = d1;
      *(u16x8*)&dst[16] = d2;
      *(u16x8*)&dst[24] = d3;
    }
    if (t >= 448){
      int p = t - 448;
      rzp[p] = 1.0f / (poss[p] + poss[64 + p]);
    }
    __syncthreads();   // B5

    // ---- w tile (ftF alias): w[p][n] = exp(S - mp)/Zp, 0 for pad n
    {
      float mpc = mpv[col];
      float rz = rzp[col];
      #pragma unroll
      for (int f = 0; f < 5; ++f){
        #pragma unroll
        for (int r = 0; r < 4; ++r){
          int rowi = nbase + 16*f + 4*lk + r;
          float wv_ = (rowi < NCLS) ? __expf(acc[f][r] - mpc) * rz : 0.f;
          wls[col*W_STRIDE + rowi] = f2h(wv_);
        }
      }
    }
    __syncthreads();   // B6

    // ---- P5: accO[c][p] = sum_n clsWT[c][n]*w[p][n]; epilogue += feat -> out1
    {
      f32x4 accO[2][4];
      #pragma unroll
      for (int f = 0; f < 2; ++f)
        #pragma unroll
        for (int pf = 0; pf < 4; ++pf) accO[f][pf] = (f32x4){0.f, 0.f, 0.f, 0.f};
      #pragma unroll
      for (int kb = 0; kb < 5; ++kb){
        int ko = kb*32 + lk*8;
        f16x8 a0 = *(const f16x8*)&clsWB[(cstrip + l15)*NPAD + ko];
        f16x8 a1 = *(const f16x8*)&clsWB[(cstrip + 16 + l15)*NPAD + ko];
        #pragma unroll
        for (int pf = 0; pf < 4; ++pf){
          f16x8 bb = *(const f16x8*)&wls[(pf*16 + l15)*W_STRIDE + ko];
          accO[0][pf] = MFMA16F(a0, bb, accO[0][pf], 0, 0, 0);
          accO[1][pf] = MFMA16F(a1, bb, accO[1][pf], 0, 0, 0);
        }
      }
      #pragma unroll
      for (int f = 0; f < 2; ++f){
        #pragma unroll
        for (int r = 0; r < 4; ++r){
          int c = cstrip + f*16 + lk*4 + r;
          float* ob = out1 + (size_t)(b*CDIM + c)*HW + p0;
          #pragma unroll
          for (int pf = 0; pf < 4; ++pf){
            int pp = pf*16 + l15;
            ob[pp] = accO[f][pf][r] + h2f(fN[c*FN_STRIDE + pp]);
          }
        }
      }
    }
    __syncthreads();   // B7
  }
}

// ---------------- k2p: per-subtile cls-softmax weights e^{m_sv - m_g}/Z
__global__ __launch_bounds__(256) void k2p(const float* __restrict__ mS, const float* __restrict__ lS,
                                           float* __restrict__ wch){
  int b = blockIdx.x / 10, nb = blockIdx.x % 10, t = threadIdx.x;
  int sg = t >> 4, j = t & 15;
  int n = nb*16 + j;
  __shared__ float pm[16][16], pz[16][16];
  float m = -3.0e38f;
  for (int i = 0; i < 16; ++i){
    int s = sg + 16*i;
    m = fmaxf(m, mS[(size_t)(b*NSV + s)*NPAD + n]);
  }
  pm[sg][j] = m;
  __syncthreads();
  float mg = pm[0][j];
  #pragma unroll
  for (int k = 1; k < 16; ++k) mg = fmaxf(mg, pm[k][j]);
  float z = 0.f;
  for (int i = 0; i < 16; ++i){
    int s = sg + 16*i;
    z += lS[(size_t)(b*NSV + s)*NPAD + n] * __expf(mS[(size_t)(b*NSV + s)*NPAD + n] - mg);
  }
  pz[sg][j] = z;
  __syncthreads();
  float Z = pz[0][j];
  #pragma unroll
  for (int k = 1; k < 16; ++k) Z += pz[k][j];
  float rZ = 1.0f / Z;
  for (int i = 0; i < 16; ++i){
    int s = sg + 16*i;
    wch[(size_t)(b*NSV + s)*NPAD + n] = __expf(mS[(size_t)(b*NSV + s)*NPAD + n] - mg) * rZ;
  }
}

// ---------------- kC: cls-value GEMM: part[c][n] = sum_p featF16[c][p] * (U[n][p]*wch[n])
__global__ __launch_bounds__(512, 4) void kC(const float* __restrict__ feat,
                                             const u16* __restrict__ Ug,
                                             const float* __restrict__ wch,
                                             u16* __restrict__ part){
  extern __shared__ char sm[];
  u16* Ul = (u16*)(sm + C_U);
  u16* fN = (u16*)(sm + C_FN);
  int b = blockIdx.x & 7, pr = blockIdx.x >> 3, t = threadIdx.x;
  const float* featG = feat + (size_t)b*(CDIM*HW);
  int lane = t & 63, wvi = t >> 6;
  int l15 = lane & 15, lk = (lane >> 4) & 3;
  int cstrip = wvi*32;

  f32x4 accC[2][10];
  #pragma unroll
  for (int f = 0; f < 2; ++f)
    #pragma unroll
    for (int nf = 0; nf < 10; ++nf) accC[f][nf] = (f32x4){0.f, 0.f, 0.f, 0.f};

  for (int sub = 0; sub < 4; ++sub){
    int sv = pr*4 + sub;
    int p0 = sv*64;
    const u16* Us = Ug + (size_t)(b*NSV + sv)*NPAD*64;
    const float* wchS = wch + (size_t)(b*NSV + sv)*NPAD;
    // stage U (scaled by wch)
    #pragma unroll
    for (int it = 0; it < 3; ++it){
      int idx = t + it*512;
      if (idx < 1280){
        int n = idx >> 3, s8 = idx & 7;
        u16x8 u = *(const u16x8*)&Us[n*64 + s8*8];
        float w = wchS[n];
        u16x8 o;
        #pragma unroll
        for (int j = 0; j < 8; ++j) o[j] = f2h(h2f(u[j]) * w);
        *(u16x8*)&Ul[n*U_STRIDE + s8*8] = o;
      }
    }
    // stage featN (f32 -> f16)
    #pragma unroll
    for (int it = 0; it < 4; ++it){
      int idx = t + it*512;
      int c = idx >> 3, s8 = idx & 7;
      const float* g = featG + (size_t)c*HW + p0 + s8*8;
      f32x4 v0 = *(const f32x4*)&g[0];
      f32x4 v1 = *(const f32x4*)&g[4];
      u16x8 o = {f2h(v0[0]), f2h(v0[1]), f2h(v0[2]), f2h(v0[3]),
                 f2h(v1[0]), f2h(v1[1]), f2h(v1[2]), f2h(v1[3])};
      *(u16x8*)&fN[c*FN_STRIDE + s8*8] = o;
    }
    __syncthreads();
    // P4 GEMM
    #pragma unroll
    for (int kb = 0; kb < 2; ++kb){
      int ko = kb*32 + lk*8;
      f16x8 a0 = *(const f16x8*)&fN[(cstrip + l15)*FN_STRIDE + ko];
      f16x8 a1 = *(const f16x8*)&fN[(cstrip + 16 + l15)*FN_STRIDE + ko];
      #pragma unroll
      for (int nf = 0; nf < 10; ++nf){
        f16x8 bb = *(const f16x8*)&Ul[(nf*16 + l15)*U_STRIDE + ko];
        accC[0][nf] = MFMA16F(a0, bb, accC[0][nf], 0, 0, 0);
        accC[1][nf] = MFMA16F(a1, bb, accC[1][nf], 0, 0, 0);
      }
    }
    __syncthreads();
  }
  // dump partials (f16, pre-normalized)
  #pragma unroll
  for (int f = 0; f < 2; ++f){
    #pragma unroll
    for (int nf = 0; nf < 10; ++nf){
      #pragma unroll
      for (int r = 0; r < 4; ++r){
        int c = cstrip + f*16 + lk*4 + r;
        int n = nf*16 + l15;
        part[((size_t)(b*64 + pr)*CDIM + c)*NPAD + n] = f2h(accC[f][nf][r]);
      }
    }
  }
}

// ---------------- k4: sum 64 partials, project with W_cls, add cls_repr -> out0
__global__ __launch_bounds__(256) void k4(const u16* __restrict__ part,
                                          const float* __restrict__ Wc,
                                          const float* __restrict__ cls, float* __restrict__ out0){
  int b = blockIdx.x / 10, nb = blockIdx.x % 10, t = threadIdx.x;
  __shared__ float comb[256][17];
  float a16[16];
  #pragma unroll
  for (int j = 0; j < 16; ++j) a16[j] = 0.f;
  for (int s = 0; s < 64; ++s){
    const u16* src = part + ((size_t)(b*64 + s)*CDIM + t)*NPAD + nb*16;
    u16x8 v0 = *(const u16x8*)&src[0];
    u16x8 v1 = *(const u16x8*)&src[8];
    #pragma unroll
    for (int j = 0; j < 8; ++j) a16[j] += h2f(v0[j]);
    #pragma unroll
    for (int j = 0; j < 8; ++j) a16[8+j] += h2f(v1[j]);
  }
  #pragma unroll
  for (int j = 0; j < 16; ++j) comb[t][j] = a16[j];
  __syncthreads();
  const float* wr = Wc + t*CDIM;
  for (int j = 0; j < 16; ++j){
    int n = nb*16 + j;
    if (n >= NCLS) break;
    float o = 0.f;
    #pragma unroll 4
    for (int c = 0; c < 256; c += 4){
      o += comb[c][j]*wr[c] + comb[c+1][j]*wr[c+1] + comb[c+2][j]*wr[c+2] + comb[c+3][j]*wr[c+3];
    }
    out0[(b*NCLS + n)*CDIM + t] = cls[(b*NCLS + n)*CDIM + t] + o;
  }
}

extern "C" void kernel_launch(void* const* d_in, const int* in_sizes, int n_in,
                              void* d_out, int out_size, void* d_ws, size_t ws_size,
                              hipStream_t stream){
  (void)in_sizes; (void)n_in; (void)out_size; (void)ws_size;
  const float* cls  = (const float*)d_in[0];   // [8][150][256]
  const float* feat = (const float*)d_in[1];   // [8][256][16384]
  const float* Wc   = (const float*)d_in[2];   // [256][256]
  const float* Wf   = (const float*)d_in[3];   // [256][256]
  float* out0 = (float*)d_out;                 // [8][150][256]
  float* out1 = out0 + 8*NCLS*CDIM;            // [8][256][16384]
  char* ws = (char*)d_ws;
  u16*  clsF  = (u16*)(ws + WS_CLSF);
  u16*  clsWT = (u16*)(ws + WS_CLSWT);
  float* mSv  = (float*)(ws + WS_MS);
  float* lSv  = (float*)(ws + WS_LS);
  float* wchv = (float*)(ws + WS_WCH);
  u16*  Ug    = (u16*)(ws + WS_U);
  u16*  partv = (u16*)(ws + WS_PART);

  hipFuncSetAttribute((const void*)kA, hipFuncAttributeMaxDynamicSharedMemorySize, A_LDS);
  hipFuncSetAttribute((const void*)kC, hipFuncAttributeMaxDynamicSharedMemorySize, C_LDS);

  k0<<<8*NPAD, 256, 0, stream>>>(cls, Wf, clsF, clsWT);
  kA<<<512, 512, A_LDS, stream>>>(feat, clsF, clsWT, Ug, mSv, lSv, out1);
  k2p<<<80, 256, 0, stream>>>(mSv, lSv, wchv);
  kC<<<512, 512, C_LDS, stream>>>(feat, Ug, wchv, partv);
  k4<<<80, 256, 0, stream>>>(partv, Wc, cls, out0);
}

// Round 5
// 640.622 us; speedup vs baseline: 1.5653x; 1.0440x over previous
//
#include <hip/hip_runtime.h>

typedef unsigned short u16;
typedef __attribute__((ext_vector_type(8))) _Float16 f16x8;
typedef __attribute__((ext_vector_type(4))) float f32x4;
typedef __attribute__((ext_vector_type(4))) unsigned short u16x4;
typedef __attribute__((ext_vector_type(8))) unsigned short u16x8;

#define MFMA16F __builtin_amdgcn_mfma_f32_16x16x32_f16

#define HW   16384
#define NCLS 150
#define NPAD 160
#define CDIM 256
#define NSV  256     // 64-px subtiles per batch

// LDS strides (shorts). byte stride % 16 == 0 (b128-aligned), % 128 != 0 (bank spread)
#define FT_STRIDE 264   // featT [64 px][256 c]
#define FN_STRIDE 72    // featN [256 c][64 px]
#define U_STRIDE  72    // U     [160 n][64 px]
#define W_STRIDE  168   // w     [64 px][160 n]

// kA LDS layout (bytes)
#define A_FT    0        // 33792; U tile (23040) then w tile (21504) alias here
#define A_FN    33792    // 36864
#define A_ROWM  70656    // [160][4] f32
#define A_ROWS  73216    // [160][4] f32
#define A_ROWMF 75776    // [160] f32
#define A_POSM  76416    // [2][64] f32
#define A_POSS  76928    // [2][64] f32
#define A_MPV   77440    // [64] f32
#define A_RZP   77696    // [64] f32
#define A_LDS   77952    // 2 blocks/CU (LDS-wise)

// kC LDS layout (bytes)
#define C_U    0         // [160][U_STRIDE] f16 = 23040
#define C_FN   23040     // [256][FN_STRIDE] f16 = 36864
#define C_LDS  59904     // 2 blocks/CU (LDS-wise)

// workspace offsets (bytes)
#define WS_CLSF  0           // [8][160][256] f16
#define WS_CLSWT 655360      // [8][256][160] f16
#define WS_MS    1310720     // [8][256][160] f32
#define WS_LS    2621440     // [8][256][160] f32
#define WS_WCH   3932160     // [8][256][160] f32
#define WS_U     5242880     // [8][256][160][64] f16 = 41,943,040
#define WS_PART  47185920    // [8][64][256][160] f16 = 20,971,520  (total 68,157,440)

__device__ __forceinline__ u16 f2h(float f){
  return __builtin_bit_cast(u16, (_Float16)f);
}
__device__ __forceinline__ float h2f(u16 h){
  return (float)__builtin_bit_cast(_Float16, h);
}

// ---------------- K0: cls -> f16 (padded to 160 rows), cls_wT = (cls @ W_f^T)^T in f16
__global__ __launch_bounds__(256) void k0(const float* __restrict__ cls, const float* __restrict__ Wf,
                                          u16* __restrict__ clsF, u16* __restrict__ clsWT){
  int b = blockIdx.x / NPAD, n = blockIdx.x % NPAD, t = threadIdx.x;
  __shared__ float row[256];
  int bn = b*NPAD + n;
  if (n < NCLS){
    float v = cls[(b*NCLS + n)*CDIM + t];
    clsF[bn*CDIM + t] = f2h(v);
    row[t] = v;
    __syncthreads();
    float acc = 0.f;
    const float* wr = Wf + t*CDIM;
    #pragma unroll 4
    for (int c = 0; c < 256; c += 4){
      acc += row[c]*wr[c] + row[c+1]*wr[c+1] + row[c+2]*wr[c+2] + row[c+3]*wr[c+3];
    }
    clsWT[(b*CDIM + t)*NPAD + n] = f2h(acc);
  } else {
    clsF[bn*CDIM + t] = 0;
    clsWT[(b*CDIM + t)*NPAD + n] = 0;
  }
}

// ---------------- kA: pos direction (out1) + U tiles + per-subtile cls stats
// NOTE: no min-occupancy arg in launch_bounds — with (512,4) the compiler capped
// VGPRs at 64 and spilled the S accumulator (rounds 3/4: VGPR_Count=64, +~500MB
// scratch HBM traffic). Plain (512) empirically allocates 128 (round 2).
__global__ __launch_bounds__(512) void kA(const float* __restrict__ feat,
                                          const u16* __restrict__ clsF,
                                          const u16* __restrict__ clsWT,
                                          u16* __restrict__ Ug,
                                          float* __restrict__ mS, float* __restrict__ lS,
                                          float* __restrict__ out1){
  extern __shared__ char sm[];
  u16*  ftF = (u16*)(sm + A_FT);
  u16*  Ul  = (u16*)(sm + A_FT);     // alias after S-GEMM
  u16*  wls = (u16*)(sm + A_FT);     // alias after U dump
  u16*  fN  = (u16*)(sm + A_FN);
  float* rowM  = (float*)(sm + A_ROWM);
  float* rowS  = (float*)(sm + A_ROWS);
  float* rowMf = (float*)(sm + A_ROWMF);
  float* posm  = (float*)(sm + A_POSM);
  float* poss  = (float*)(sm + A_POSS);
  float* mpv   = (float*)(sm + A_MPV);
  float* rzp   = (float*)(sm + A_RZP);

  int b = blockIdx.x & 7, blk = blockIdx.x >> 3, t = threadIdx.x;
  const float* featG = feat + (size_t)b*(CDIM*HW);
  const u16* clsB  = clsF  + b*NPAD*CDIM;
  const u16* clsWB = clsWT + b*CDIM*NPAD;

  int lane = t & 63, wvi = t >> 6;
  int l15 = lane & 15, lk = (lane >> 4) & 3;
  int nh = wvi >> 2, pq = wvi & 3;
  int nbase = nh*80;
  int col = pq*16 + l15;
  int cstrip = wvi*32;

  for (int sub = 0; sub < 4; ++sub){
    int sv = blk*4 + sub;
    int p0 = sv*64;
    // ---- stage featT [p][c] + featN [c][p] (f16)
    {
      int p = t & 63, cg = t >> 6;
      #pragma unroll
      for (int i = 0; i < 8; ++i){
        int c0 = (i*8 + cg)*4;
        const float* g0 = featG + (size_t)c0*HW + p0 + p;
        float v0 = g0[0];
        float v1 = g0[HW];
        float v2 = g0[2*HW];
        float v3 = g0[3*HW];
        u16 h0 = f2h(v0), h1 = f2h(v1), h2 = f2h(v2), h3 = f2h(v3);
        u16x4 hv = {h0, h1, h2, h3};
        *(u16x4*)&ftF[p*FT_STRIDE + c0] = hv;
        fN[(c0+0)*FN_STRIDE + p] = h0;
        fN[(c0+1)*FN_STRIDE + p] = h1;
        fN[(c0+2)*FN_STRIDE + p] = h2;
        fN[(c0+3)*FN_STRIDE + p] = h3;
      }
    }
    __syncthreads();   // B1

    // ---- S-GEMM into registers: acc[f][r] = S[nbase+16f+4lk+r][col]  (kept as S)
    f32x4 acc[5];
    #pragma unroll
    for (int f = 0; f < 5; ++f) acc[f] = (f32x4){0.f, 0.f, 0.f, 0.f};
    #pragma unroll
    for (int kb = 0; kb < 8; ++kb){
      int ko = kb*32 + lk*8;
      f16x8 bh = *(const f16x8*)&ftF[(pq*16 + l15)*FT_STRIDE + ko];
      #pragma unroll
      for (int f = 0; f < 5; ++f){
        f16x8 ah = *(const f16x8*)&clsB[(nbase + f*16 + l15)*CDIM + ko];
        acc[f] = MFMA16F(ah, bh, acc[f], 0, 0, 0);
      }
    }

    // ---- wave-local row (cls) stats: m,l over this wave's 16 cols
    #pragma unroll
    for (int f = 0; f < 5; ++f){
      #pragma unroll
      for (int r = 0; r < 4; ++r){
        float v = acc[f][r];
        float m = v;
        m = fmaxf(m, __shfl_xor(m, 1));
        m = fmaxf(m, __shfl_xor(m, 2));
        m = fmaxf(m, __shfl_xor(m, 4));
        m = fmaxf(m, __shfl_xor(m, 8));
        float s = __expf(v - m);
        s += __shfl_xor(s, 1);
        s += __shfl_xor(s, 2);
        s += __shfl_xor(s, 4);
        s += __shfl_xor(s, 8);
        if (l15 == f){
          int rowi = nbase + 16*f + 4*lk + r;
          rowM[rowi*4 + pq] = m;
          rowS[rowi*4 + pq] = s;
        }
      }
    }
    // ---- pos (per-pixel) max over valid n
    {
      float pmax = -3.0e38f;
      #pragma unroll
      for (int f = 0; f < 5; ++f)
        #pragma unroll
        for (int r = 0; r < 4; ++r){
          int rowi = nbase + 16*f + 4*lk + r;
          if (rowi < NCLS) pmax = fmaxf(pmax, acc[f][r]);
        }
      pmax = fmaxf(pmax, __shfl_xor(pmax, 16));
      pmax = fmaxf(pmax, __shfl_xor(pmax, 32));
      if (lk == 0) posm[nh*64 + col] = pmax;
    }
    __syncthreads();   // B2

    // ---- combine: per-subtile cls stats -> global; pos max combine
    if (t < NPAD){
      float rm0 = rowM[t*4+0], rm1 = rowM[t*4+1], rm2 = rowM[t*4+2], rm3 = rowM[t*4+3];
      float msub = fmaxf(fmaxf(rm0, rm1), fmaxf(rm2, rm3));
      float l = rowS[t*4+0]*__expf(rm0 - msub) + rowS[t*4+1]*__expf(rm1 - msub)
              + rowS[t*4+2]*__expf(rm2 - msub) + rowS[t*4+3]*__expf(rm3 - msub);
      rowMf[t] = msub;
      mS[(size_t)(b*NSV + sv)*NPAD + t] = msub;
      lS[(size_t)(b*NSV + sv)*NPAD + t] = l;
    }
    if (t >= 448){
      int p = t - 448;
      mpv[p] = fmaxf(posm[p], posm[64 + p]);
    }
    __syncthreads();   // B3

    // ---- U tile (ftF alias): U[n][p] = exp(S - m_sub[n]); pos-sum partials
    {
      float mpc = mpv[col];
      float s = 0.f;
      #pragma unroll
      for (int f = 0; f < 5; ++f){
        #pragma unroll
        for (int r = 0; r < 4; ++r){
          int rowi = nbase + 16*f + 4*lk + r;
          Ul[rowi*U_STRIDE + col] = f2h(__expf(acc[f][r] - rowMf[rowi]));
          if (rowi < NCLS) s += __expf(acc[f][r] - mpc);
        }
      }
      s += __shfl_xor(s, 16);
      s += __shfl_xor(s, 32);
      if (lk == 0) poss[nh*64 + col] = s;
    }
    __syncthreads();   // B4

    // ---- dump U tile to global (coalesced 64-B chunks); rzp
    if (t < 320){
      int n = t >> 1, half = t & 1;
      const u16* srcL = &Ul[n*U_STRIDE + half*32];
      u16x8 d0 = *(const u16x8*)&srcL[0];
      u16x8 d1 = *(const u16x8*)&srcL[8];
      u16x8 d2 = *(const u16x8*)&srcL[16];
      u16x8 d3 = *(const u16x8*)&srcL[24];
      u16* dst = Ug + ((size_t)(b*NSV + sv)*NPAD + n)*64 + half*32;
      *(u16x8*)&dst[0]  = d0;
      *(u16x8*)&dst[8]  = d1;
      *(u16x8*)&dst[16] = d2;
      *(u16x8*)&dst[24] = d3;
    }
    if (t >= 448){
      int p = t - 448;
      rzp[p] = 1.0f / (poss[p] + poss[64 + p]);
    }
    __syncthreads();   // B5

    // ---- w tile (ftF alias): w[p][n] = exp(S - mp)/Zp, 0 for pad n
    {
      float mpc = mpv[col];
      float rz = rzp[col];
      #pragma unroll
      for (int f = 0; f < 5; ++f){
        #pragma unroll
        for (int r = 0; r < 4; ++r){
          int rowi = nbase + 16*f + 4*lk + r;
          float wv_ = (rowi < NCLS) ? __expf(acc[f][r] - mpc) * rz : 0.f;
          wls[col*W_STRIDE + rowi] = f2h(wv_);
        }
      }
    }
    __syncthreads();   // B6

    // ---- P5: accO[c][p] = sum_n clsWT[c][n]*w[p][n]; epilogue += feat -> out1
    {
      f32x4 accO[2][4];
      #pragma unroll
      for (int f = 0; f < 2; ++f)
        #pragma unroll
        for (int pf = 0; pf < 4; ++pf) accO[f][pf] = (f32x4){0.f, 0.f, 0.f, 0.f};
      #pragma unroll
      for (int kb = 0; kb < 5; ++kb){
        int ko = kb*32 + lk*8;
        f16x8 a0 = *(const f16x8*)&clsWB[(cstrip + l15)*NPAD + ko];
        f16x8 a1 = *(const f16x8*)&clsWB[(cstrip + 16 + l15)*NPAD + ko];
        #pragma unroll
        for (int pf = 0; pf < 4; ++pf){
          f16x8 bb = *(const f16x8*)&wls[(pf*16 + l15)*W_STRIDE + ko];
          accO[0][pf] = MFMA16F(a0, bb, accO[0][pf], 0, 0, 0);
          accO[1][pf] = MFMA16F(a1, bb, accO[1][pf], 0, 0, 0);
        }
      }
      #pragma unroll
      for (int f = 0; f < 2; ++f){
        #pragma unroll
        for (int r = 0; r < 4; ++r){
          int c = cstrip + f*16 + lk*4 + r;
          float* ob = out1 + (size_t)(b*CDIM + c)*HW + p0;
          #pragma unroll
          for (int pf = 0; pf < 4; ++pf){
            int pp = pf*16 + l15;
            ob[pp] = accO[f][pf][r] + h2f(fN[c*FN_STRIDE + pp]);
          }
        }
      }
    }
    __syncthreads();   // B7
  }
}

// ---------------- k2p: per-subtile cls-softmax weights e^{m_sv - m_g}/Z
__global__ __launch_bounds__(256) void k2p(const float* __restrict__ mS, const float* __restrict__ lS,
                                           float* __restrict__ wch){
  int b = blockIdx.x / 10, nb = blockIdx.x % 10, t = threadIdx.x;
  int sg = t >> 4, j = t & 15;
  int n = nb*16 + j;
  __shared__ float pm[16][16], pz[16][16];
  float m = -3.0e38f;
  for (int i = 0; i < 16; ++i){
    int s = sg + 16*i;
    m = fmaxf(m, mS[(size_t)(b*NSV + s)*NPAD + n]);
  }
  pm[sg][j] = m;
  __syncthreads();
  float mg = pm[0][j];
  #pragma unroll
  for (int k = 1; k < 16; ++k) mg = fmaxf(mg, pm[k][j]);
  float z = 0.f;
  for (int i = 0; i < 16; ++i){
    int s = sg + 16*i;
    z += lS[(size_t)(b*NSV + s)*NPAD + n] * __expf(mS[(size_t)(b*NSV + s)*NPAD + n] - mg);
  }
  pz[sg][j] = z;
  __syncthreads();
  float Z = pz[0][j];
  #pragma unroll
  for (int k = 1; k < 16; ++k) Z += pz[k][j];
  float rZ = 1.0f / Z;
  for (int i = 0; i < 16; ++i){
    int s = sg + 16*i;
    wch[(size_t)(b*NSV + s)*NPAD + n] = __expf(mS[(size_t)(b*NSV + s)*NPAD + n] - mg) * rZ;
  }
}

// ---------------- kC: cls-value GEMM: part[c][n] = sum_p featF16[c][p] * (U[n][p]*wch[n])
__global__ __launch_bounds__(512) void kC(const float* __restrict__ feat,
                                          const u16* __restrict__ Ug,
                                          const float* __restrict__ wch,
                                          u16* __restrict__ part){
  extern __shared__ char sm[];
  u16* Ul = (u16*)(sm + C_U);
  u16* fN = (u16*)(sm + C_FN);
  int b = blockIdx.x & 7, pr = blockIdx.x >> 3, t = threadIdx.x;
  const float* featG = feat + (size_t)b*(CDIM*HW);
  int lane = t & 63, wvi = t >> 6;
  int l15 = lane & 15, lk = (lane >> 4) & 3;
  int cstrip = wvi*32;

  f32x4 accC[2][10];
  #pragma unroll
  for (int f = 0; f < 2; ++f)
    #pragma unroll
    for (int nf = 0; nf < 10; ++nf) accC[f][nf] = (f32x4){0.f, 0.f, 0.f, 0.f};

  for (int sub = 0; sub < 4; ++sub){
    int sv = pr*4 + sub;
    int p0 = sv*64;
    const u16* Us = Ug + (size_t)(b*NSV + sv)*NPAD*64;
    const float* wchS = wch + (size_t)(b*NSV + sv)*NPAD;
    // stage U (scaled by wch)
    #pragma unroll
    for (int it = 0; it < 3; ++it){
      int idx = t + it*512;
      if (idx < 1280){
        int n = idx >> 3, s8 = idx & 7;
        u16x8 u = *(const u16x8*)&Us[n*64 + s8*8];
        float w = wchS[n];
        u16x8 o;
        #pragma unroll
        for (int j = 0; j < 8; ++j) o[j] = f2h(h2f(u[j]) * w);
        *(u16x8*)&Ul[n*U_STRIDE + s8*8] = o;
      }
    }
    // stage featN (f32 -> f16)
    #pragma unroll
    for (int it = 0; it < 4; ++it){
      int idx = t + it*512;
      int c = idx >> 3, s8 = idx & 7;
      const float* g = featG + (size_t)c*HW + p0 + s8*8;
      f32x4 v0 = *(const f32x4*)&g[0];
      f32x4 v1 = *(const f32x4*)&g[4];
      u16x8 o = {f2h(v0[0]), f2h(v0[1]), f2h(v0[2]), f2h(v0[3]),
                 f2h(v1[0]), f2h(v1[1]), f2h(v1[2]), f2h(v1[3])};
      *(u16x8*)&fN[c*FN_STRIDE + s8*8] = o;
    }
    __syncthreads();
    // P4 GEMM
    #pragma unroll
    for (int kb = 0; kb < 2; ++kb){
      int ko = kb*32 + lk*8;
      f16x8 a0 = *(const f16x8*)&fN[(cstrip + l15)*FN_STRIDE + ko];
      f16x8 a1 = *(const f16x8*)&fN[(cstrip + 16 + l15)*FN_STRIDE + ko];
      #pragma unroll
      for (int nf = 0; nf < 10; ++nf){
        f16x8 bb = *(const f16x8*)&Ul[(nf*16 + l15)*U_STRIDE + ko];
        accC[0][nf] = MFMA16F(a0, bb, accC[0][nf], 0, 0, 0);
        accC[1][nf] = MFMA16F(a1, bb, accC[1][nf], 0, 0, 0);
      }
    }
    __syncthreads();
  }
  // dump partials (f16, pre-normalized)
  #pragma unroll
  for (int f = 0; f < 2; ++f){
    #pragma unroll
    for (int nf = 0; nf < 10; ++nf){
      #pragma unroll
      for (int r = 0; r < 4; ++r){
        int c = cstrip + f*16 + lk*4 + r;
        int n = nf*16 + l15;
        part[((size_t)(b*64 + pr)*CDIM + c)*NPAD + n] = f2h(accC[f][nf][r]);
      }
    }
  }
}

// ---------------- k4: sum 64 partials, project with W_cls, add cls_repr -> out0
__global__ __launch_bounds__(256) void k4(const u16* __restrict__ part,
                                          const float* __restrict__ Wc,
                                          const float* __restrict__ cls, float* __restrict__ out0){
  int b = blockIdx.x / 10, nb = blockIdx.x % 10, t = threadIdx.x;
  __shared__ float comb[256][17];
  float a16[16];
  #pragma unroll
  for (int j = 0; j < 16; ++j) a16[j] = 0.f;
  for (int s = 0; s < 64; ++s){
    const u16* src = part + ((size_t)(b*64 + s)*CDIM + t)*NPAD + nb*16;
    u16x8 v0 = *(const u16x8*)&src[0];
    u16x8 v1 = *(const u16x8*)&src[8];
    #pragma unroll
    for (int j = 0; j < 8; ++j) a16[j] += h2f(v0[j]);
    #pragma unroll
    for (int j = 0; j < 8; ++j) a16[8+j] += h2f(v1[j]);
  }
  #pragma unroll
  for (int j = 0; j < 16; ++j) comb[t][j] = a16[j];
  __syncthreads();
  const float* wr = Wc + t*CDIM;
  for (int j = 0; j < 16; ++j){
    int n = nb*16 + j;
    if (n >= NCLS) break;
    float o = 0.f;
    #pragma unroll 4
    for (int c = 0; c < 256; c += 4){
      o += comb[c][j]*wr[c] + comb[c+1][j]*wr[c+1] + comb[c+2][j]*wr[c+2] + comb[c+3][j]*wr[c+3];
    }
    out0[(b*NCLS + n)*CDIM + t] = cls[(b*NCLS + n)*CDIM + t] + o;
  }
}

extern "C" void kernel_launch(void* const* d_in, const int* in_sizes, int n_in,
                              void* d_out, int out_size, void* d_ws, size_t ws_size,
                              hipStream_t stream){
  (void)in_sizes; (void)n_in; (void)out_size; (void)ws_size;
  const float* cls  = (const float*)d_in[0];   // [8][150][256]
  const float* feat = (const float*)d_in[1];   // [8][256][16384]
  const float* Wc   = (const float*)d_in[2];   // [256][256]
  const float* Wf   = (const float*)d_in[3];   // [256][256]
  float* out0 = (float*)d_out;                 // [8][150][256]
  float* out1 = out0 + 8*NCLS*CDIM;            // [8][256][16384]
  char* ws = (char*)d_ws;
  u16*  clsF  = (u16*)(ws + WS_CLSF);
  u16*  clsWT = (u16*)(ws + WS_CLSWT);
  float* mSv  = (float*)(ws + WS_MS);
  float* lSv  = (float*)(ws + WS_LS);
  float* wchv = (float*)(ws + WS_WCH);
  u16*  Ug    = (u16*)(ws + WS_U);
  u16*  partv = (u16*)(ws + WS_PART);

  hipFuncSetAttribute((const void*)kA, hipFuncAttributeMaxDynamicSharedMemorySize, A_LDS);
  hipFuncSetAttribute((const void*)kC, hipFuncAttributeMaxDynamicSharedMemorySize, C_LDS);

  k0<<<8*NPAD, 256, 0, stream>>>(cls, Wf, clsF, clsWT);
  kA<<<512, 512, A_LDS, stream>>>(feat, clsF, clsWT, Ug, mSv, lSv, out1);
  k2p<<<80, 256, 0, stream>>>(mSv, lSv, wchv);
  kC<<<512, 512, C_LDS, stream>>>(feat, Ug, wchv, partv);
  k4<<<80, 256, 0, stream>>>(partv, Wc, cls, out0);
}

// Round 6
// 409.257 us; speedup vs baseline: 2.4502x; 1.5653x over previous
//
#include <hip/hip_runtime.h>

typedef unsigned short u16;
typedef __attribute__((ext_vector_type(8))) _Float16 f16x8;
typedef __attribute__((ext_vector_type(4))) float f32x4;
typedef __attribute__((ext_vector_type(4))) unsigned short u16x4;
typedef __attribute__((ext_vector_type(8))) unsigned short u16x8;

#define MFMA16F __builtin_amdgcn_mfma_f32_16x16x32_f16

#define HW   16384
#define NCLS 150
#define NPAD 160
#define CDIM 256

// LDS strides (shorts)
#define FT_STRIDE 264   // featT [64 px][256 c]
#define FN_STRIDE 72    // featN [256 c][64 px]
#define EP_STRIDE 72    // E'    [160 n][64 px]
#define W_STRIDE  168   // E^T   [64 px][160 n]

// workspace offsets (bytes); total 65,939,456 <= proven 68,157,440
#define WS_CLSF  0          // [8][160][256] f16
#define WS_CLSWT 655360     // [8][256][160] f16
#define WS_MP    1310720    // [8][16384] f32 per-pixel max
#define WS_RZP   1835008    // [8][16384] f32 per-pixel 1/Z
#define WS_ROWP  2359296    // [8][64][160][2] f32 row (m,l) block partials
#define WS_MG    3014656    // [8][160] f32 global row max
#define WS_RZ    3019776    // [8][160] f32 global row 1/Z
#define WS_S     3024896    // [8][160][16384] f16 = 41,943,040
#define WS_PART  44967936   // [8][32][256][160] f16 = 20,971,520

__device__ __forceinline__ u16 f2h(float f){ return __builtin_bit_cast(u16, (_Float16)f); }
__device__ __forceinline__ float h2f(u16 h){ return (float)__builtin_bit_cast(_Float16, h); }

// ---------------- k0: cls -> f16 (padded 160 rows, pads zero), clsWT = (cls @ Wf^T)^T f16
__global__ __launch_bounds__(256) void k0(const float* __restrict__ cls, const float* __restrict__ Wf,
                                          u16* __restrict__ clsF, u16* __restrict__ clsWT){
  int b = blockIdx.x / NPAD, n = blockIdx.x % NPAD, t = threadIdx.x;
  __shared__ float row[256];
  int bn = b*NPAD + n;
  if (n < NCLS){
    float v = cls[(b*NCLS + n)*CDIM + t];
    clsF[bn*CDIM + t] = f2h(v);
    row[t] = v;
    __syncthreads();
    float acc = 0.f;
    const float* wr = Wf + t*CDIM;
    #pragma unroll 4
    for (int c = 0; c < 256; c += 4){
      acc += row[c]*wr[c] + row[c+1]*wr[c+1] + row[c+2]*wr[c+2] + row[c+3]*wr[c+3];
    }
    clsWT[(b*CDIM + t)*NPAD + n] = f2h(acc);
  } else {
    clsF[bn*CDIM + t] = 0;
    clsWT[(b*CDIM + t)*NPAD + n] = 0;
  }
}

// ---------------- kS: S[n][p] = cls . feat  (one 160x64 tile per block, 1 barrier)
__global__ __launch_bounds__(512) void kS(const float* __restrict__ feat, const u16* __restrict__ clsF,
                                          u16* __restrict__ Sg){
  extern __shared__ char sm[];
  u16* ftF = (u16*)sm;   // [64][FT_STRIDE]
  int b = blockIdx.x & 7, tl = blockIdx.x >> 3, t = threadIdx.x;
  int p0 = tl*64;
  const float* featG = feat + (size_t)b*(CDIM*HW);
  const u16* clsB = clsF + b*NPAD*CDIM;
  {
    int p = t & 63, cg = t >> 6;
    #pragma unroll
    for (int i = 0; i < 8; ++i){
      int c0 = (i*8 + cg)*4;
      const float* g0 = featG + (size_t)c0*HW + p0 + p;
      float v0 = g0[0], v1 = g0[HW], v2 = g0[2*HW], v3 = g0[3*HW];
      u16x4 hv = {f2h(v0), f2h(v1), f2h(v2), f2h(v3)};
      *(u16x4*)&ftF[p*FT_STRIDE + c0] = hv;
    }
  }
  __syncthreads();
  int lane = t & 63, wv = t >> 6;
  int l15 = lane & 15, lk = (lane >> 4) & 3;
  int nh = wv >> 2, pq = wv & 3;
  int nbase = nh*80;
  f32x4 acc[5];
  #pragma unroll
  for (int f = 0; f < 5; ++f) acc[f] = (f32x4){0.f,0.f,0.f,0.f};
  #pragma unroll
  for (int kb = 0; kb < 8; ++kb){
    int ko = kb*32 + lk*8;
    f16x8 bh = *(const f16x8*)&ftF[(pq*16 + l15)*FT_STRIDE + ko];
    #pragma unroll
    for (int f = 0; f < 5; ++f){
      f16x8 ah = *(const f16x8*)&clsB[(nbase + f*16 + l15)*CDIM + ko];
      acc[f] = MFMA16F(ah, bh, acc[f], 0, 0, 0);
    }
  }
  u16* Sb = Sg + (size_t)b*NPAD*HW;
  int pcol = p0 + pq*16 + l15;
  #pragma unroll
  for (int f = 0; f < 5; ++f){
    #pragma unroll
    for (int r = 0; r < 4; ++r){
      int n = nbase + 16*f + 4*lk + r;
      Sb[(size_t)n*HW + pcol] = f2h(acc[f][r]);
    }
  }
}

// ---------------- kStat: one pass over S -> per-pixel (mp, rzp) + per-row block partials
__global__ __launch_bounds__(512) void kStat(const u16* __restrict__ Sg,
                                             float* __restrict__ mp, float* __restrict__ rzp,
                                             float* __restrict__ rowP){
  __shared__ float pcM[16*256];
  __shared__ float pcL[16*256];
  __shared__ float rMs[NPAD], rLs[NPAD];
  int b = blockIdx.x & 7, blk = blockIdx.x >> 3, t = threadIdx.x;
  int p0 = blk*256;
  const u16* Sb = Sg + (size_t)b*NPAD*HW;
  int grp = t >> 5, px8 = (t & 31)*8;
  float pm[8], pl[8];
  #pragma unroll
  for (int j = 0; j < 8; ++j){ pm[j] = -3.0e38f; pl[j] = 0.f; }
  for (int ps = 0; ps < 10; ++ps){
    int rowi = ps*16 + grp;
    u16x8 v = *(const u16x8*)&Sb[(size_t)rowi*HW + p0 + px8];
    float vf[8];
    #pragma unroll
    for (int j = 0; j < 8; ++j) vf[j] = h2f(v[j]);
    // row (cls) direction partial over this thread's 8 px
    float rm = vf[0];
    #pragma unroll
    for (int j = 1; j < 8; ++j) rm = fmaxf(rm, vf[j]);
    float rl = 0.f;
    #pragma unroll
    for (int j = 0; j < 8; ++j) rl += __expf(vf[j] - rm);
    // combine across the 32 lanes sharing this row
    #pragma unroll
    for (int d = 1; d < 32; d <<= 1){
      float om = __shfl_xor(rm, d), ol = __shfl_xor(rl, d);
      float mn = fmaxf(rm, om);
      rl = rl*__expf(rm - mn) + ol*__expf(om - mn);
      rm = mn;
    }
    if ((t & 31) == 0){ rMs[rowi] = rm; rLs[rowi] = rl; }
    // pixel (pos) direction online update (exclude pad rows)
    if (rowi < NCLS){
      #pragma unroll
      for (int j = 0; j < 8; ++j){
        float m2 = fmaxf(pm[j], vf[j]);
        pl[j] = pl[j]*__expf(pm[j] - m2) + __expf(vf[j] - m2);
        pm[j] = m2;
      }
    }
  }
  #pragma unroll
  for (int j = 0; j < 8; ++j){
    pcM[grp*256 + px8 + j] = pm[j];
    pcL[grp*256 + px8 + j] = pl[j];
  }
  __syncthreads();
  if (t < 256){
    float m = -3.0e38f, l = 0.f;
    for (int g = 0; g < 16; ++g){
      float gm = pcM[g*256 + t], gl = pcL[g*256 + t];
      float mn = fmaxf(m, gm);
      l = l*__expf(m - mn) + gl*__expf(gm - mn);
      m = mn;
    }
    mp[((size_t)b << 14) + p0 + t] = m;
    rzp[((size_t)b << 14) + p0 + t] = 1.0f / l;
  } else if (t < 256 + NPAD){
    int n = t - 256;
    float* rp = rowP + ((size_t)(b*64 + blk)*NPAD + n)*2;
    rp[0] = rMs[n];
    rp[1] = rLs[n];
  }
}

// ---------------- kComb: reduce 64 row-partials -> m_g, rZ
__global__ __launch_bounds__(256) void kComb(const float* __restrict__ rowP,
                                             float* __restrict__ mg, float* __restrict__ rz){
  int b = blockIdx.x, t = threadIdx.x;
  if (t < NPAD){
    float m = -3.0e38f, l = 0.f;
    for (int s = 0; s < 64; ++s){
      const float* rp = rowP + ((size_t)(b*64 + s)*NPAD + t)*2;
      float ms = rp[0], ls = rp[1];
      float mn = fmaxf(m, ms);
      l = l*__expf(m - mn) + ls*__expf(ms - mn);
      m = mn;
    }
    mg[b*NPAD + t] = m;
    rz[b*NPAD + t] = 1.0f / l;
  }
}

// ---------------- kOut1: out1[c][p] = feat + clsWT . softmax_pos(S)  (one 64-px tile/block)
__global__ __launch_bounds__(512) void kOut1(const u16* __restrict__ Sg, const u16* __restrict__ clsWT,
                                             const float* __restrict__ mp, const float* __restrict__ rzp,
                                             const float* __restrict__ feat, float* __restrict__ out1){
  extern __shared__ char sm[];
  u16* E = (u16*)sm;  // [64 px][W_STRIDE n]
  int b = blockIdx.x & 7, tl = blockIdx.x >> 3, t = threadIdx.x;
  int p0 = tl*64;
  const u16* Sb = Sg + (size_t)b*NPAD*HW;
  const u16* clsWB = clsWT + b*CDIM*NPAD;
  const float* mpB = mp + ((size_t)b << 14) + p0;
  const float* rzB = rzp + ((size_t)b << 14) + p0;
  {
    int rr = t >> 3, px8 = (t & 7)*8;
    #pragma unroll
    for (int ps = 0; ps < 3; ++ps){
      int rowi = ps*64 + rr;
      if (rowi < NPAD){
        float ev[8];
        if (rowi < NCLS){
          u16x8 v = *(const u16x8*)&Sb[(size_t)rowi*HW + p0 + px8];
          #pragma unroll
          for (int j = 0; j < 8; ++j) ev[j] = __expf(h2f(v[j]) - mpB[px8 + j]);
        } else {
          #pragma unroll
          for (int j = 0; j < 8; ++j) ev[j] = 0.f;
        }
        #pragma unroll
        for (int j = 0; j < 8; ++j) E[(px8 + j)*W_STRIDE + rowi] = f2h(ev[j]);
      }
    }
  }
  __syncthreads();
  int lane = t & 63, wv = t >> 6;
  int l15 = lane & 15, lk = (lane >> 4) & 3;
  int cstrip = wv*32;
  f32x4 acc[2][4];
  #pragma unroll
  for (int cf = 0; cf < 2; ++cf)
    #pragma unroll
    for (int pf = 0; pf < 4; ++pf) acc[cf][pf] = (f32x4){0.f,0.f,0.f,0.f};
  #pragma unroll
  for (int kb = 0; kb < 5; ++kb){
    int ko = kb*32 + lk*8;
    f16x8 a0 = *(const f16x8*)&clsWB[(cstrip + l15)*NPAD + ko];
    f16x8 a1 = *(const f16x8*)&clsWB[(cstrip + 16 + l15)*NPAD + ko];
    #pragma unroll
    for (int pf = 0; pf < 4; ++pf){
      f16x8 bb = *(const f16x8*)&E[(pf*16 + l15)*W_STRIDE + ko];
      acc[0][pf] = MFMA16F(a0, bb, acc[0][pf], 0, 0, 0);
      acc[1][pf] = MFMA16F(a1, bb, acc[1][pf], 0, 0, 0);
    }
  }
  const float* featB = feat + (size_t)b*CDIM*HW;
  #pragma unroll
  for (int cf = 0; cf < 2; ++cf){
    #pragma unroll
    for (int r = 0; r < 4; ++r){
      int c = cstrip + cf*16 + lk*4 + r;
      const float* fr = featB + (size_t)c*HW + p0;
      float* ob = out1 + (size_t)(b*CDIM + c)*HW + p0;
      #pragma unroll
      for (int pf = 0; pf < 4; ++pf){
        int pp = pf*16 + l15;
        ob[pp] = acc[cf][pf][r]*rzB[pp] + fr[pp];
      }
    }
  }
}

// ---------------- kOut0: part[c][n] = sum_p featF16[c][p] * exp(S - m_g[n])  (512 px/block)
__global__ __launch_bounds__(512) void kOut0(const u16* __restrict__ Sg, const float* __restrict__ feat,
                                             const float* __restrict__ mg, u16* __restrict__ part){
  extern __shared__ char sm[];
  u16* Ep = (u16*)sm;                        // [NPAD][EP_STRIDE]
  u16* fN = (u16*)(sm + NPAD*EP_STRIDE*2);   // [CDIM][FN_STRIDE]
  int b = blockIdx.x & 7, pr = blockIdx.x >> 3, t = threadIdx.x;
  const u16* Sb = Sg + (size_t)b*NPAD*HW;
  const float* featB = feat + (size_t)b*CDIM*HW;
  const float* mgB = mg + b*NPAD;
  int lane = t & 63, wv = t >> 6;
  int l15 = lane & 15, lk = (lane >> 4) & 3;
  int cstrip = wv*32;
  int rr = t >> 3, px8 = (t & 7)*8;
  f32x4 acc[2][10];
  #pragma unroll
  for (int cf = 0; cf < 2; ++cf)
    #pragma unroll
    for (int nf = 0; nf < 10; ++nf) acc[cf][nf] = (f32x4){0.f,0.f,0.f,0.f};
  for (int ck = 0; ck < 8; ++ck){
    int p0 = pr*512 + ck*64;
    #pragma unroll
    for (int ps = 0; ps < 3; ++ps){
      int rowi = ps*64 + rr;
      if (rowi < NPAD){
        u16x8 v = *(const u16x8*)&Sb[(size_t)rowi*HW + p0 + px8];
        float m = mgB[rowi];
        u16x8 o;
        #pragma unroll
        for (int j = 0; j < 8; ++j) o[j] = f2h(__expf(h2f(v[j]) - m));
        *(u16x8*)&Ep[rowi*EP_STRIDE + px8] = o;
      }
    }
    #pragma unroll
    for (int ps = 0; ps < 4; ++ps){
      int c = ps*64 + rr;
      const float* g = featB + (size_t)c*HW + p0 + px8;
      f32x4 v0 = *(const f32x4*)&g[0];
      f32x4 v1 = *(const f32x4*)&g[4];
      u16x8 o = {f2h(v0[0]), f2h(v0[1]), f2h(v0[2]), f2h(v0[3]),
                 f2h(v1[0]), f2h(v1[1]), f2h(v1[2]), f2h(v1[3])};
      *(u16x8*)&fN[c*FN_STRIDE + px8] = o;
    }
    __syncthreads();
    #pragma unroll
    for (int kb = 0; kb < 2; ++kb){
      int ko = kb*32 + lk*8;
      f16x8 a0 = *(const f16x8*)&fN[(cstrip + l15)*FN_STRIDE + ko];
      f16x8 a1 = *(const f16x8*)&fN[(cstrip + 16 + l15)*FN_STRIDE + ko];
      #pragma unroll
      for (int nf = 0; nf < 10; ++nf){
        f16x8 bb = *(const f16x8*)&Ep[(nf*16 + l15)*EP_STRIDE + ko];
        acc[0][nf] = MFMA16F(a0, bb, acc[0][nf], 0, 0, 0);
        acc[1][nf] = MFMA16F(a1, bb, acc[1][nf], 0, 0, 0);
      }
    }
    __syncthreads();
  }
  #pragma unroll
  for (int cf = 0; cf < 2; ++cf){
    #pragma unroll
    for (int nf = 0; nf < 10; ++nf){
      #pragma unroll
      for (int r = 0; r < 4; ++r){
        int c = cstrip + cf*16 + lk*4 + r;
        int n = nf*16 + l15;
        part[((size_t)(b*32 + pr)*CDIM + c)*NPAD + n] = f2h(acc[cf][nf][r]);
      }
    }
  }
}

// ---------------- k4: sum 32 partials, apply rZ, project Wc, residual -> out0
__global__ __launch_bounds__(256) void k4(const u16* __restrict__ part, const float* __restrict__ rz,
                                          const float* __restrict__ Wc,
                                          const float* __restrict__ cls, float* __restrict__ out0){
  int b = blockIdx.x / 10, nb = blockIdx.x % 10, t = threadIdx.x;
  __shared__ float comb[256][17];
  float a16[16];
  #pragma unroll
  for (int j = 0; j < 16; ++j) a16[j] = 0.f;
  for (int s = 0; s < 32; ++s){
    const u16* src = part + ((size_t)(b*32 + s)*CDIM + t)*NPAD + nb*16;
    u16x8 v0 = *(const u16x8*)&src[0];
    u16x8 v1 = *(const u16x8*)&src[8];
    #pragma unroll
    for (int j = 0; j < 8; ++j) a16[j] += h2f(v0[j]);
    #pragma unroll
    for (int j = 0; j < 8; ++j) a16[8+j] += h2f(v1[j]);
  }
  #pragma unroll
  for (int j = 0; j < 16; ++j) comb[t][j] = a16[j] * rz[b*NPAD + nb*16 + j];
  __syncthreads();
  const float* wr = Wc + t*CDIM;
  for (int j = 0; j < 16; ++j){
    int n = nb*16 + j;
    if (n >= NCLS) break;
    float o = 0.f;
    #pragma unroll 4
    for (int c = 0; c < 256; c += 4){
      o += comb[c][j]*wr[c] + comb[c+1][j]*wr[c+1] + comb[c+2][j]*wr[c+2] + comb[c+3][j]*wr[c+3];
    }
    out0[(b*NCLS + n)*CDIM + t] = cls[(b*NCLS + n)*CDIM + t] + o;
  }
}

extern "C" void kernel_launch(void* const* d_in, const int* in_sizes, int n_in,
                              void* d_out, int out_size, void* d_ws, size_t ws_size,
                              hipStream_t stream){
  (void)in_sizes; (void)n_in; (void)out_size; (void)ws_size;
  const float* cls  = (const float*)d_in[0];   // [8][150][256]
  const float* feat = (const float*)d_in[1];   // [8][256][16384]
  const float* Wc   = (const float*)d_in[2];   // [256][256]
  const float* Wf   = (const float*)d_in[3];   // [256][256]
  float* out0 = (float*)d_out;                 // [8][150][256]
  float* out1 = out0 + 8*NCLS*CDIM;            // [8][256][16384]
  char* ws = (char*)d_ws;
  u16*   clsF  = (u16*)(ws + WS_CLSF);
  u16*   clsWT = (u16*)(ws + WS_CLSWT);
  float* mpv   = (float*)(ws + WS_MP);
  float* rzpv  = (float*)(ws + WS_RZP);
  float* rowPv = (float*)(ws + WS_ROWP);
  float* mgv   = (float*)(ws + WS_MG);
  float* rzv   = (float*)(ws + WS_RZ);
  u16*   Sgp   = (u16*)(ws + WS_S);
  u16*   partv = (u16*)(ws + WS_PART);

  k0   <<<8*NPAD, 256, 0, stream>>>(cls, Wf, clsF, clsWT);
  kS   <<<2048, 512, 64*FT_STRIDE*2, stream>>>(feat, clsF, Sgp);
  kStat<<<512, 512, 0, stream>>>(Sgp, mpv, rzpv, rowPv);
  kComb<<<8, 256, 0, stream>>>(rowPv, mgv, rzv);
  kOut1<<<2048, 512, 64*W_STRIDE*2, stream>>>(Sgp, clsWT, mpv, rzpv, feat, out1);
  kOut0<<<256, 512, (NPAD*EP_STRIDE + CDIM*FN_STRIDE)*2, stream>>>(Sgp, feat, mgv, partv);
  k4   <<<80, 256, 0, stream>>>(partv, rzv, Wc, cls, out0);
}

// Round 7
// 298.574 us; speedup vs baseline: 3.3585x; 1.3707x over previous
//
#include <hip/hip_runtime.h>

typedef unsigned short u16;
typedef __attribute__((ext_vector_type(8))) _Float16 f16x8;
typedef __attribute__((ext_vector_type(4))) float f32x4;
typedef __attribute__((ext_vector_type(4))) unsigned short u16x4;
typedef __attribute__((ext_vector_type(8))) unsigned short u16x8;

#define MFMA16F __builtin_amdgcn_mfma_f32_16x16x32_f16

#define HW   16384
#define NCLS 150
#define NPAD 160
#define CDIM 256

// LDS strides (shorts)
#define FT_STRIDE 264   // featT [64 px][256 c]
#define FN_STRIDE 72    // featN [256 c][64 px]
#define EP_STRIDE 72    // E'    [160 n][64 px]
#define W_STRIDE  168   // E^T   [64 px][160 n]
#define CT_STRIDE 264   // combT tile [80 n][256 k]

// workspace offsets (bytes); total 66,725,888 <= proven 68,157,440
#define WS_CLSF  0          // [8][160][256] f16
#define WS_CLSWT 655360     // [8][256][160] f16
#define WS_MP    1310720    // [8][16384] f32 per-pixel max
#define WS_RZP   1835008    // [8][16384] f32 per-pixel 1/Z
#define WS_ROWP  2359296    // [8][64][160][2] f32 row (m,l) block partials
#define WS_MG    3014656    // [8][160] f32 global row max
#define WS_RZ    3019776    // [8][160] f32 global row 1/Z
#define WS_S     3024896    // [8][160][16384] f16 = 41,943,040
#define WS_PART  44967936   // [8][32][256][160] f16 = 20,971,520
#define WS_COMBT 65939456   // [8][160][256] f16 = 655,360  (rZ-scaled reduced partials)
#define WS_WCF   66594816   // [256][256] f16 = 131,072

__device__ __forceinline__ u16 f2h(float f){ return __builtin_bit_cast(u16, (_Float16)f); }
__device__ __forceinline__ float h2f(u16 h){ return (float)__builtin_bit_cast(_Float16, h); }

// ---------------- k0: cls -> f16 (padded 160 rows, pads zero), clsWT = (cls @ Wf^T)^T f16
__global__ __launch_bounds__(256) void k0(const float* __restrict__ cls, const float* __restrict__ Wf,
                                          u16* __restrict__ clsF, u16* __restrict__ clsWT){
  int b = blockIdx.x / NPAD, n = blockIdx.x % NPAD, t = threadIdx.x;
  __shared__ float row[256];
  int bn = b*NPAD + n;
  if (n < NCLS){
    float v = cls[(b*NCLS + n)*CDIM + t];
    clsF[bn*CDIM + t] = f2h(v);
    row[t] = v;
    __syncthreads();
    float acc = 0.f;
    const float* wr = Wf + t*CDIM;
    #pragma unroll 4
    for (int c = 0; c < 256; c += 4){
      acc += row[c]*wr[c] + row[c+1]*wr[c+1] + row[c+2]*wr[c+2] + row[c+3]*wr[c+3];
    }
    clsWT[(b*CDIM + t)*NPAD + n] = f2h(acc);
  } else {
    clsF[bn*CDIM + t] = 0;
    clsWT[(b*CDIM + t)*NPAD + n] = 0;
  }
}

// ---------------- kW: Wc f32 -> f16
__global__ __launch_bounds__(512) void kW(const float* __restrict__ Wc, u16* __restrict__ WcF){
  int i = (blockIdx.x*512 + threadIdx.x)*4;
  f32x4 v = *(const f32x4*)&Wc[i];
  u16x4 o = {f2h(v[0]), f2h(v[1]), f2h(v[2]), f2h(v[3])};
  *(u16x4*)&WcF[i] = o;
}

// ---------------- kS: S[n][p] = cls . feat  (one 160x64 tile per block, 1 barrier)
__global__ __launch_bounds__(512) void kS(const float* __restrict__ feat, const u16* __restrict__ clsF,
                                          u16* __restrict__ Sg){
  extern __shared__ char sm[];
  u16* ftF = (u16*)sm;   // [64][FT_STRIDE]
  int b = blockIdx.x & 7, tl = blockIdx.x >> 3, t = threadIdx.x;
  int p0 = tl*64;
  const float* featG = feat + (size_t)b*(CDIM*HW);
  const u16* clsB = clsF + b*NPAD*CDIM;
  {
    int p = t & 63, cg = t >> 6;
    #pragma unroll
    for (int i = 0; i < 8; ++i){
      int c0 = (i*8 + cg)*4;
      const float* g0 = featG + (size_t)c0*HW + p0 + p;
      float v0 = g0[0], v1 = g0[HW], v2 = g0[2*HW], v3 = g0[3*HW];
      u16x4 hv = {f2h(v0), f2h(v1), f2h(v2), f2h(v3)};
      *(u16x4*)&ftF[p*FT_STRIDE + c0] = hv;
    }
  }
  __syncthreads();
  int lane = t & 63, wv = t >> 6;
  int l15 = lane & 15, lk = (lane >> 4) & 3;
  int nh = wv >> 2, pq = wv & 3;
  int nbase = nh*80;
  f32x4 acc[5];
  #pragma unroll
  for (int f = 0; f < 5; ++f) acc[f] = (f32x4){0.f,0.f,0.f,0.f};
  #pragma unroll
  for (int kb = 0; kb < 8; ++kb){
    int ko = kb*32 + lk*8;
    f16x8 bh = *(const f16x8*)&ftF[(pq*16 + l15)*FT_STRIDE + ko];
    #pragma unroll
    for (int f = 0; f < 5; ++f){
      f16x8 ah = *(const f16x8*)&clsB[(nbase + f*16 + l15)*CDIM + ko];
      acc[f] = MFMA16F(ah, bh, acc[f], 0, 0, 0);
    }
  }
  u16* Sb = Sg + (size_t)b*NPAD*HW;
  int pcol = p0 + pq*16 + l15;
  #pragma unroll
  for (int f = 0; f < 5; ++f){
    #pragma unroll
    for (int r = 0; r < 4; ++r){
      int n = nbase + 16*f + 4*lk + r;
      Sb[(size_t)n*HW + pcol] = f2h(acc[f][r]);
    }
  }
}

// ---------------- kStat: one pass over S -> per-pixel (mp, rzp) + per-row block partials
__global__ __launch_bounds__(512) void kStat(const u16* __restrict__ Sg,
                                             float* __restrict__ mp, float* __restrict__ rzp,
                                             float* __restrict__ rowP){
  __shared__ float pcM[16*256];
  __shared__ float pcL[16*256];
  __shared__ float rMs[NPAD], rLs[NPAD];
  int b = blockIdx.x & 7, blk = blockIdx.x >> 3, t = threadIdx.x;
  int p0 = blk*256;
  const u16* Sb = Sg + (size_t)b*NPAD*HW;
  int grp = t >> 5, px8 = (t & 31)*8;
  float pm[8], pl[8];
  #pragma unroll
  for (int j = 0; j < 8; ++j){ pm[j] = -3.0e38f; pl[j] = 0.f; }
  for (int ps = 0; ps < 10; ++ps){
    int rowi = ps*16 + grp;
    u16x8 v = *(const u16x8*)&Sb[(size_t)rowi*HW + p0 + px8];
    float vf[8];
    #pragma unroll
    for (int j = 0; j < 8; ++j) vf[j] = h2f(v[j]);
    float rm = vf[0];
    #pragma unroll
    for (int j = 1; j < 8; ++j) rm = fmaxf(rm, vf[j]);
    float rl = 0.f;
    #pragma unroll
    for (int j = 0; j < 8; ++j) rl += __expf(vf[j] - rm);
    #pragma unroll
    for (int d = 1; d < 32; d <<= 1){
      float om = __shfl_xor(rm, d), ol = __shfl_xor(rl, d);
      float mn = fmaxf(rm, om);
      rl = rl*__expf(rm - mn) + ol*__expf(om - mn);
      rm = mn;
    }
    if ((t & 31) == 0){ rMs[rowi] = rm; rLs[rowi] = rl; }
    if (rowi < NCLS){
      #pragma unroll
      for (int j = 0; j < 8; ++j){
        float m2 = fmaxf(pm[j], vf[j]);
        pl[j] = pl[j]*__expf(pm[j] - m2) + __expf(vf[j] - m2);
        pm[j] = m2;
      }
    }
  }
  #pragma unroll
  for (int j = 0; j < 8; ++j){
    pcM[grp*256 + px8 + j] = pm[j];
    pcL[grp*256 + px8 + j] = pl[j];
  }
  __syncthreads();
  if (t < 256){
    float m = -3.0e38f, l = 0.f;
    for (int g = 0; g < 16; ++g){
      float gm = pcM[g*256 + t], gl = pcL[g*256 + t];
      float mn = fmaxf(m, gm);
      l = l*__expf(m - mn) + gl*__expf(gm - mn);
      m = mn;
    }
    mp[((size_t)b << 14) + p0 + t] = m;
    rzp[((size_t)b << 14) + p0 + t] = 1.0f / l;
  } else if (t < 256 + NPAD){
    int n = t - 256;
    float* rp = rowP + ((size_t)(b*64 + blk)*NPAD + n)*2;
    rp[0] = rMs[n];
    rp[1] = rLs[n];
  }
}

// ---------------- kComb: reduce 64 row-partials -> m_g, rZ
__global__ __launch_bounds__(256) void kComb(const float* __restrict__ rowP,
                                             float* __restrict__ mg, float* __restrict__ rz){
  int b = blockIdx.x, t = threadIdx.x;
  if (t < NPAD){
    float m = -3.0e38f, l = 0.f;
    for (int s = 0; s < 64; ++s){
      const float* rp = rowP + ((size_t)(b*64 + s)*NPAD + t)*2;
      float ms = rp[0], ls = rp[1];
      float mn = fmaxf(m, ms);
      l = l*__expf(m - mn) + ls*__expf(ms - mn);
      m = mn;
    }
    mg[b*NPAD + t] = m;
    rz[b*NPAD + t] = 1.0f / l;
  }
}

// ---------------- kOut1: out1[c][p] = feat + clsWT . softmax_pos(S)  (one 64-px tile/block)
__global__ __launch_bounds__(512) void kOut1(const u16* __restrict__ Sg, const u16* __restrict__ clsWT,
                                             const float* __restrict__ mp, const float* __restrict__ rzp,
                                             const float* __restrict__ feat, float* __restrict__ out1){
  extern __shared__ char sm[];
  u16* E = (u16*)sm;  // [64 px][W_STRIDE n]
  int b = blockIdx.x & 7, tl = blockIdx.x >> 3, t = threadIdx.x;
  int p0 = tl*64;
  const u16* Sb = Sg + (size_t)b*NPAD*HW;
  const u16* clsWB = clsWT + b*CDIM*NPAD;
  const float* mpB = mp + ((size_t)b << 14) + p0;
  const float* rzB = rzp + ((size_t)b << 14) + p0;
  {
    int rr = t >> 3, px8 = (t & 7)*8;
    #pragma unroll
    for (int ps = 0; ps < 3; ++ps){
      int rowi = ps*64 + rr;
      if (rowi < NPAD){
        float ev[8];
        if (rowi < NCLS){
          u16x8 v = *(const u16x8*)&Sb[(size_t)rowi*HW + p0 + px8];
          #pragma unroll
          for (int j = 0; j < 8; ++j) ev[j] = __expf(h2f(v[j]) - mpB[px8 + j]);
        } else {
          #pragma unroll
          for (int j = 0; j < 8; ++j) ev[j] = 0.f;
        }
        #pragma unroll
        for (int j = 0; j < 8; ++j) E[(px8 + j)*W_STRIDE + rowi] = f2h(ev[j]);
      }
    }
  }
  __syncthreads();
  int lane = t & 63, wv = t >> 6;
  int l15 = lane & 15, lk = (lane >> 4) & 3;
  int cstrip = wv*32;
  f32x4 acc[2][4];
  #pragma unroll
  for (int cf = 0; cf < 2; ++cf)
    #pragma unroll
    for (int pf = 0; pf < 4; ++pf) acc[cf][pf] = (f32x4){0.f,0.f,0.f,0.f};
  #pragma unroll
  for (int kb = 0; kb < 5; ++kb){
    int ko = kb*32 + lk*8;
    f16x8 a0 = *(const f16x8*)&clsWB[(cstrip + l15)*NPAD + ko];
    f16x8 a1 = *(const f16x8*)&clsWB[(cstrip + 16 + l15)*NPAD + ko];
    #pragma unroll
    for (int pf = 0; pf < 4; ++pf){
      f16x8 bb = *(const f16x8*)&E[(pf*16 + l15)*W_STRIDE + ko];
      acc[0][pf] = MFMA16F(a0, bb, acc[0][pf], 0, 0, 0);
      acc[1][pf] = MFMA16F(a1, bb, acc[1][pf], 0, 0, 0);
    }
  }
  const float* featB = feat + (size_t)b*CDIM*HW;
  #pragma unroll
  for (int cf = 0; cf < 2; ++cf){
    #pragma unroll
    for (int r = 0; r < 4; ++r){
      int c = cstrip + cf*16 + lk*4 + r;
      const float* fr = featB + (size_t)c*HW + p0;
      float* ob = out1 + (size_t)(b*CDIM + c)*HW + p0;
      #pragma unroll
      for (int pf = 0; pf < 4; ++pf){
        int pp = pf*16 + l15;
        ob[pp] = acc[cf][pf][r]*rzB[pp] + fr[pp];
      }
    }
  }
}

// ---------------- kOut0: part[c][n] = sum_p featF16[c][p] * exp(S - m_g[n])  (512 px/block)
__global__ __launch_bounds__(512) void kOut0(const u16* __restrict__ Sg, const float* __restrict__ feat,
                                             const float* __restrict__ mg, u16* __restrict__ part){
  extern __shared__ char sm[];
  u16* Ep = (u16*)sm;                        // [NPAD][EP_STRIDE]
  u16* fN = (u16*)(sm + NPAD*EP_STRIDE*2);   // [CDIM][FN_STRIDE]
  int b = blockIdx.x & 7, pr = blockIdx.x >> 3, t = threadIdx.x;
  const u16* Sb = Sg + (size_t)b*NPAD*HW;
  const float* featB = feat + (size_t)b*CDIM*HW;
  const float* mgB = mg + b*NPAD;
  int lane = t & 63, wv = t >> 6;
  int l15 = lane & 15, lk = (lane >> 4) & 3;
  int cstrip = wv*32;
  int rr = t >> 3, px8 = (t & 7)*8;
  f32x4 acc[2][10];
  #pragma unroll
  for (int cf = 0; cf < 2; ++cf)
    #pragma unroll
    for (int nf = 0; nf < 10; ++nf) acc[cf][nf] = (f32x4){0.f,0.f,0.f,0.f};
  for (int ck = 0; ck < 8; ++ck){
    int p0 = pr*512 + ck*64;
    #pragma unroll
    for (int ps = 0; ps < 3; ++ps){
      int rowi = ps*64 + rr;
      if (rowi < NPAD){
        u16x8 v = *(const u16x8*)&Sb[(size_t)rowi*HW + p0 + px8];
        float m = mgB[rowi];
        u16x8 o;
        #pragma unroll
        for (int j = 0; j < 8; ++j) o[j] = f2h(__expf(h2f(v[j]) - m));
        *(u16x8*)&Ep[rowi*EP_STRIDE + px8] = o;
      }
    }
    #pragma unroll
    for (int ps = 0; ps < 4; ++ps){
      int c = ps*64 + rr;
      const float* g = featB + (size_t)c*HW + p0 + px8;
      f32x4 v0 = *(const f32x4*)&g[0];
      f32x4 v1 = *(const f32x4*)&g[4];
      u16x8 o = {f2h(v0[0]), f2h(v0[1]), f2h(v0[2]), f2h(v0[3]),
                 f2h(v1[0]), f2h(v1[1]), f2h(v1[2]), f2h(v1[3])};
      *(u16x8*)&fN[c*FN_STRIDE + px8] = o;
    }
    __syncthreads();
    #pragma unroll
    for (int kb = 0; kb < 2; ++kb){
      int ko = kb*32 + lk*8;
      f16x8 a0 = *(const f16x8*)&fN[(cstrip + l15)*FN_STRIDE + ko];
      f16x8 a1 = *(const f16x8*)&fN[(cstrip + 16 + l15)*FN_STRIDE + ko];
      #pragma unroll
      for (int nf = 0; nf < 10; ++nf){
        f16x8 bb = *(const f16x8*)&Ep[(nf*16 + l15)*EP_STRIDE + ko];
        acc[0][nf] = MFMA16F(a0, bb, acc[0][nf], 0, 0, 0);
        acc[1][nf] = MFMA16F(a1, bb, acc[1][nf], 0, 0, 0);
      }
    }
    __syncthreads();
  }
  #pragma unroll
  for (int cf = 0; cf < 2; ++cf){
    #pragma unroll
    for (int nf = 0; nf < 10; ++nf){
      #pragma unroll
      for (int r = 0; r < 4; ++r){
        int c = cstrip + cf*16 + lk*4 + r;
        int n = nf*16 + l15;
        part[((size_t)(b*32 + pr)*CDIM + c)*NPAD + n] = f2h(acc[cf][nf][r]);
      }
    }
  }
}

// ---------------- k4a: streaming reduce of part over 32 chunks, fold rZ -> combT[b][n][c] f16
__global__ __launch_bounds__(256) void k4a(const u16* __restrict__ part, const float* __restrict__ rz,
                                           u16* __restrict__ combT){
  int b = blockIdx.x / 20, sub = blockIdx.x % 20, t = threadIdx.x;
  int idx8 = (sub*256 + t)*8;          // flat (c*160+n), 8 contiguous n
  int c = idx8 / NPAD, n0 = idx8 % NPAD;
  const u16* base = part + (size_t)(b*32)*CDIM*NPAD + idx8;
  float a[8];
  #pragma unroll
  for (int j = 0; j < 8; ++j) a[j] = 0.f;
  for (int s = 0; s < 32; ++s){
    u16x8 v = *(const u16x8*)&base[(size_t)s*CDIM*NPAD];
    #pragma unroll
    for (int j = 0; j < 8; ++j) a[j] += h2f(v[j]);
  }
  const float* rzB = rz + b*NPAD + n0;
  #pragma unroll
  for (int j = 0; j < 8; ++j){
    combT[((size_t)(b*NPAD) + n0 + j)*CDIM + c] = f2h(a[j] * rzB[j]);
  }
}

// ---------------- k4b: out0[n][c] = cls + combT[n][:] @ WcF[c][:]  (MFMA, 80 n-rows/block)
__global__ __launch_bounds__(512) void k4b(const u16* __restrict__ combT, const u16* __restrict__ WcF,
                                           const float* __restrict__ cls, float* __restrict__ out0){
  extern __shared__ char sm[];
  u16* A = (u16*)sm;   // [80][CT_STRIDE]
  int b = blockIdx.x >> 1, nb = blockIdx.x & 1, t = threadIdx.x;
  const u16* cb = combT + (size_t)(b*NPAD + nb*80)*CDIM;
  // stage 80x256 tile
  #pragma unroll
  for (int it = 0; it < 10; ++it){
    int idx8 = (it*512 + t)*8;
    if (idx8 < 80*256){
      int row = idx8 >> 8, k0 = idx8 & 255;
      u16x8 v = *(const u16x8*)&cb[idx8];
      *(u16x8*)&A[row*CT_STRIDE + k0] = v;
    }
  }
  __syncthreads();
  int lane = t & 63, wv = t >> 6;
  int l15 = lane & 15, lk = (lane >> 4) & 3;
  int cstrip = wv*32;
  f32x4 acc[5][2];
  #pragma unroll
  for (int f = 0; f < 5; ++f)
    #pragma unroll
    for (int ct = 0; ct < 2; ++ct) acc[f][ct] = (f32x4){0.f,0.f,0.f,0.f};
  #pragma unroll
  for (int kb = 0; kb < 8; ++kb){
    int ko = kb*32 + lk*8;
    f16x8 b0 = *(const f16x8*)&WcF[(cstrip + l15)*CDIM + ko];
    f16x8 b1 = *(const f16x8*)&WcF[(cstrip + 16 + l15)*CDIM + ko];
    #pragma unroll
    for (int f = 0; f < 5; ++f){
      f16x8 af = *(const f16x8*)&A[(f*16 + l15)*CT_STRIDE + ko];
      acc[f][0] = MFMA16F(af, b0, acc[f][0], 0, 0, 0);
      acc[f][1] = MFMA16F(af, b1, acc[f][1], 0, 0, 0);
    }
  }
  #pragma unroll
  for (int f = 0; f < 5; ++f){
    #pragma unroll
    for (int r = 0; r < 4; ++r){
      int n = nb*80 + f*16 + lk*4 + r;
      if (n < NCLS){
        #pragma unroll
        for (int ct = 0; ct < 2; ++ct){
          int c = cstrip + ct*16 + l15;
          out0[(size_t)(b*NCLS + n)*CDIM + c] = cls[(size_t)(b*NCLS + n)*CDIM + c] + acc[f][ct][r];
        }
      }
    }
  }
}

extern "C" void kernel_launch(void* const* d_in, const int* in_sizes, int n_in,
                              void* d_out, int out_size, void* d_ws, size_t ws_size,
                              hipStream_t stream){
  (void)in_sizes; (void)n_in; (void)out_size; (void)ws_size;
  const float* cls  = (const float*)d_in[0];   // [8][150][256]
  const float* feat = (const float*)d_in[1];   // [8][256][16384]
  const float* Wc   = (const float*)d_in[2];   // [256][256]
  const float* Wf   = (const float*)d_in[3];   // [256][256]
  float* out0 = (float*)d_out;                 // [8][150][256]
  float* out1 = out0 + 8*NCLS*CDIM;            // [8][256][16384]
  char* ws = (char*)d_ws;
  u16*   clsF   = (u16*)(ws + WS_CLSF);
  u16*   clsWT  = (u16*)(ws + WS_CLSWT);
  float* mpv    = (float*)(ws + WS_MP);
  float* rzpv   = (float*)(ws + WS_RZP);
  float* rowPv  = (float*)(ws + WS_ROWP);
  float* mgv    = (float*)(ws + WS_MG);
  float* rzv    = (float*)(ws + WS_RZ);
  u16*   Sgp    = (u16*)(ws + WS_S);
  u16*   partv  = (u16*)(ws + WS_PART);
  u16*   combTv = (u16*)(ws + WS_COMBT);
  u16*   WcFv   = (u16*)(ws + WS_WCF);

  k0   <<<8*NPAD, 256, 0, stream>>>(cls, Wf, clsF, clsWT);
  kW   <<<32, 512, 0, stream>>>(Wc, WcFv);
  kS   <<<2048, 512, 64*FT_STRIDE*2, stream>>>(feat, clsF, Sgp);
  kStat<<<512, 512, 0, stream>>>(Sgp, mpv, rzpv, rowPv);
  kComb<<<8, 256, 0, stream>>>(rowPv, mgv, rzv);
  kOut1<<<2048, 512, 64*W_STRIDE*2, stream>>>(Sgp, clsWT, mpv, rzpv, feat, out1);
  kOut0<<<256, 512, (NPAD*EP_STRIDE + CDIM*FN_STRIDE)*2, stream>>>(Sgp, feat, mgv, partv);
  k4a  <<<160, 256, 0, stream>>>(partv, rzv, combTv);
  k4b  <<<16, 512, 80*CT_STRIDE*2, stream>>>(combTv, WcFv, cls, out0);
}

// Round 8
// 269.905 us; speedup vs baseline: 3.7153x; 1.1062x over previous
//
#include <hip/hip_runtime.h>

typedef unsigned short u16;
typedef __attribute__((ext_vector_type(8))) _Float16 f16x8;
typedef __attribute__((ext_vector_type(4))) float f32x4;
typedef __attribute__((ext_vector_type(4))) unsigned short u16x4;
typedef __attribute__((ext_vector_type(8))) unsigned short u16x8;

#define MFMA16F __builtin_amdgcn_mfma_f32_16x16x32_f16

#define HW   16384
#define NCLS 150
#define NPAD 160
#define CDIM 256

// LDS strides (shorts)
#define FT_STRIDE 264   // featT [64 px][256 c]
#define FN_STRIDE 72    // featN [256 c][64 px]
#define EP_STRIDE 72    // E'    [160 n][64 px]
#define W_STRIDE  168   // E^T   [64 px][160 n]
#define CT_STRIDE 264   // combT tile [80 n][256 k]

// kS2 LDS layout (bytes)
#define S2_FT   0        // 33792
#define S2_ROWM 33792    // [160][4] f32 = 2560
#define S2_ROWS 36352    // [160][4] f32 = 2560
#define S2_POSM 38912    // [2][64] f32 = 512
#define S2_POSS 39424    // [2][64] f32 = 512
#define S2_LDS  39936

// workspace offsets (bytes); total 66,070,528 <= proven 66,725,888
// NOTE: PART aliases ROWP (rowP dead after kComb; part written by kOut0 which runs later)
#define WS_CLSF  0          // [8][160][256] f16 = 655,360
#define WS_CLSWT 655360     // [8][256][160] f16 = 655,360
#define WS_MP    1310720    // [8][16384] f32 = 524,288
#define WS_RZP   1835008    // [8][16384] f32 = 524,288
#define WS_MG    2359296    // [8][160] f32 = 5,120
#define WS_RZ    2364416    // [8][160] f32 = 5,120
#define WS_WCF   2369536    // [256][256] f16 = 131,072
#define WS_COMBT 2500608    // [8][160][256] f16 = 655,360
#define WS_ROWP  3155968    // [8][256][160][2] f32 = 2,621,440
#define WS_PART  3155968    // [8][32][256][160] f16 = 20,971,520 (aliases ROWP)
#define WS_S     24127488   // [8][160][16384] f16 = 41,943,040 -> end 66,070,528

__device__ __forceinline__ u16 f2h(float f){ return __builtin_bit_cast(u16, (_Float16)f); }
__device__ __forceinline__ float h2f(u16 h){ return (float)__builtin_bit_cast(_Float16, h); }

// ---------------- k0: cls -> f16 (padded 160 rows, pads zero), clsWT = (cls @ Wf^T)^T f16
__global__ __launch_bounds__(256) void k0(const float* __restrict__ cls, const float* __restrict__ Wf,
                                          u16* __restrict__ clsF, u16* __restrict__ clsWT){
  int b = blockIdx.x / NPAD, n = blockIdx.x % NPAD, t = threadIdx.x;
  __shared__ float row[256];
  int bn = b*NPAD + n;
  if (n < NCLS){
    float v = cls[(b*NCLS + n)*CDIM + t];
    clsF[bn*CDIM + t] = f2h(v);
    row[t] = v;
    __syncthreads();
    float acc = 0.f;
    const float* wr = Wf + t*CDIM;
    #pragma unroll 4
    for (int c = 0; c < 256; c += 4){
      acc += row[c]*wr[c] + row[c+1]*wr[c+1] + row[c+2]*wr[c+2] + row[c+3]*wr[c+3];
    }
    clsWT[(b*CDIM + t)*NPAD + n] = f2h(acc);
  } else {
    clsF[bn*CDIM + t] = 0;
    clsWT[(b*CDIM + t)*NPAD + n] = 0;
  }
}

// ---------------- kW: Wc f32 -> f16
__global__ __launch_bounds__(512) void kW(const float* __restrict__ Wc, u16* __restrict__ WcF){
  int i = (blockIdx.x*512 + threadIdx.x)*4;
  f32x4 v = *(const f32x4*)&Wc[i];
  u16x4 o = {f2h(v[0]), f2h(v[1]), f2h(v[2]), f2h(v[3])};
  *(u16x4*)&WcF[i] = o;
}

// ---------------- kS2: S tile GEMM + fused both-direction softmax stats
// One 160x64 tile per block. A-fragments (cls, L2-resident) use 2-deep register
// double-buffer prefetch to break the load->MFMA latency chain (r7: VGPR=28, serial).
__global__ __launch_bounds__(512) void kS2(const float* __restrict__ feat, const u16* __restrict__ clsF,
                                           u16* __restrict__ Sg,
                                           float* __restrict__ mp, float* __restrict__ rzp,
                                           float* __restrict__ rowP){
  extern __shared__ char sm[];
  u16*  ftF  = (u16*)(sm + S2_FT);
  float* rowM = (float*)(sm + S2_ROWM);
  float* rowS = (float*)(sm + S2_ROWS);
  float* posm = (float*)(sm + S2_POSM);
  float* poss = (float*)(sm + S2_POSS);
  int b = blockIdx.x & 7, tl = blockIdx.x >> 3, t = threadIdx.x;
  int p0 = tl*64;
  const float* featG = feat + (size_t)b*(CDIM*HW);
  const u16* clsB = clsF + b*NPAD*CDIM;
  // ---- stage featT f16 [p][c]
  {
    int p = t & 63, cg = t >> 6;
    #pragma unroll
    for (int i = 0; i < 8; ++i){
      int c0 = (i*8 + cg)*4;
      const float* g0 = featG + (size_t)c0*HW + p0 + p;
      float v0 = g0[0], v1 = g0[HW], v2 = g0[2*HW], v3 = g0[3*HW];
      u16x4 hv = {f2h(v0), f2h(v1), f2h(v2), f2h(v3)};
      *(u16x4*)&ftF[p*FT_STRIDE + c0] = hv;
    }
  }
  __syncthreads();   // B1
  int lane = t & 63, wv = t >> 6;
  int l15 = lane & 15, lk = (lane >> 4) & 3;
  int nh = wv >> 2, pq = wv & 3;
  int nbase = nh*80;
  int col = pq*16 + l15;
  // ---- S-GEMM with prefetched A fragments
  f32x4 acc[5];
  #pragma unroll
  for (int f = 0; f < 5; ++f) acc[f] = (f32x4){0.f,0.f,0.f,0.f};
  f16x8 ah[2][5];
  #pragma unroll
  for (int f = 0; f < 5; ++f)
    ah[0][f] = *(const f16x8*)&clsB[(nbase + f*16 + l15)*CDIM + lk*8];
  #pragma unroll
  for (int kb = 0; kb < 8; ++kb){
    int cur = kb & 1;
    if (kb < 7){
      #pragma unroll
      for (int f = 0; f < 5; ++f)
        ah[cur^1][f] = *(const f16x8*)&clsB[(nbase + f*16 + l15)*CDIM + (kb+1)*32 + lk*8];
    }
    f16x8 bh = *(const f16x8*)&ftF[(pq*16 + l15)*FT_STRIDE + kb*32 + lk*8];
    #pragma unroll
    for (int f = 0; f < 5; ++f)
      acc[f] = MFMA16F(ah[cur][f], bh, acc[f], 0, 0, 0);
  }
  // ---- write S f16 (stores drain while stats compute)
  {
    u16* Sb = Sg + (size_t)b*NPAD*HW;
    int pcol = p0 + col;
    #pragma unroll
    for (int f = 0; f < 5; ++f){
      #pragma unroll
      for (int r = 0; r < 4; ++r){
        int n = nbase + 16*f + 4*lk + r;
        Sb[(size_t)n*HW + pcol] = f2h(acc[f][r]);
      }
    }
  }
  // ---- row (cls) stats: per-row (m,s) over this wave's 16 cols
  #pragma unroll
  for (int f = 0; f < 5; ++f){
    #pragma unroll
    for (int r = 0; r < 4; ++r){
      float v = acc[f][r];
      float m = v;
      m = fmaxf(m, __shfl_xor(m, 1));
      m = fmaxf(m, __shfl_xor(m, 2));
      m = fmaxf(m, __shfl_xor(m, 4));
      m = fmaxf(m, __shfl_xor(m, 8));
      float s = __expf(v - m);
      s += __shfl_xor(s, 1);
      s += __shfl_xor(s, 2);
      s += __shfl_xor(s, 4);
      s += __shfl_xor(s, 8);
      if (l15 == f){
        int rowi = nbase + 16*f + 4*lk + r;
        rowM[rowi*4 + pq] = m;
        rowS[rowi*4 + pq] = s;
      }
    }
  }
  // ---- pixel (pos) stats: per-col (m,s) over this wave's valid rows, merged across lk
  {
    float pm = -3.0e38f;
    #pragma unroll
    for (int f = 0; f < 5; ++f)
      #pragma unroll
      for (int r = 0; r < 4; ++r){
        int rowi = nbase + 16*f + 4*lk + r;
        if (rowi < NCLS) pm = fmaxf(pm, acc[f][r]);
      }
    float ps = 0.f;
    #pragma unroll
    for (int f = 0; f < 5; ++f)
      #pragma unroll
      for (int r = 0; r < 4; ++r){
        int rowi = nbase + 16*f + 4*lk + r;
        if (rowi < NCLS) ps += __expf(acc[f][r] - pm);
      }
    #pragma unroll
    for (int d = 16; d <= 32; d <<= 1){
      float om = __shfl_xor(pm, d), os = __shfl_xor(ps, d);
      float mn = fmaxf(pm, om);
      ps = ps*__expf(pm - mn) + os*__expf(om - mn);
      pm = mn;
    }
    if (lk == 0){ posm[nh*64 + col] = pm; poss[nh*64 + col] = ps; }
  }
  __syncthreads();   // B2
  // ---- combine + global stat writes
  if (t < NPAD){
    float rm0 = rowM[t*4+0], rm1 = rowM[t*4+1], rm2 = rowM[t*4+2], rm3 = rowM[t*4+3];
    float msub = fmaxf(fmaxf(rm0, rm1), fmaxf(rm2, rm3));
    float l = rowS[t*4+0]*__expf(rm0 - msub) + rowS[t*4+1]*__expf(rm1 - msub)
            + rowS[t*4+2]*__expf(rm2 - msub) + rowS[t*4+3]*__expf(rm3 - msub);
    float* rp = rowP + ((size_t)(b*256 + tl)*NPAD + t)*2;
    rp[0] = msub;
    rp[1] = l;
  }
  if (t >= 448){
    int p = t - 448;
    float m0 = posm[p], m1 = posm[64 + p];
    float mx = fmaxf(m0, m1);
    float Z = poss[p]*__expf(m0 - mx) + poss[64 + p]*__expf(m1 - mx);
    mp[((size_t)b << 14) + p0 + p] = mx;
    rzp[((size_t)b << 14) + p0 + p] = 1.0f / Z;
  }
}

// ---------------- kComb: reduce 256 row-partials -> m_g, rZ (2-level tree)
__global__ __launch_bounds__(256) void kComb(const float* __restrict__ rowP,
                                             float* __restrict__ mg, float* __restrict__ rz){
  int b = blockIdx.x / 10, nb = blockIdx.x % 10, t = threadIdx.x;
  int sg = t >> 4, j = t & 15;
  int n = nb*16 + j;
  __shared__ float pm[16][16], pl[16][16];
  float m = -3.0e38f, l = 0.f;
  for (int i = 0; i < 16; ++i){
    int s = sg + 16*i;
    const float* rp = rowP + ((size_t)(b*256 + s)*NPAD + n)*2;
    float ms = rp[0], ls = rp[1];
    float mn = fmaxf(m, ms);
    l = l*__expf(m - mn) + ls*__expf(ms - mn);
    m = mn;
  }
  pm[sg][j] = m;
  pl[sg][j] = l;
  __syncthreads();
  if (sg == 0){
    float M = pm[0][j], L = pl[0][j];
    #pragma unroll
    for (int k = 1; k < 16; ++k){
      float ms = pm[k][j], ls = pl[k][j];
      float mn = fmaxf(M, ms);
      L = L*__expf(M - mn) + ls*__expf(ms - mn);
      M = mn;
    }
    mg[b*NPAD + n] = M;
    rz[b*NPAD + n] = 1.0f / L;
  }
}

// ---------------- kOut1: out1[c][p] = feat + clsWT . softmax_pos(S)  (one 64-px tile/block)
__global__ __launch_bounds__(512) void kOut1(const u16* __restrict__ Sg, const u16* __restrict__ clsWT,
                                             const float* __restrict__ mp, const float* __restrict__ rzp,
                                             const float* __restrict__ feat, float* __restrict__ out1){
  extern __shared__ char sm[];
  u16* E = (u16*)sm;  // [64 px][W_STRIDE n]
  int b = blockIdx.x & 7, tl = blockIdx.x >> 3, t = threadIdx.x;
  int p0 = tl*64;
  const u16* Sb = Sg + (size_t)b*NPAD*HW;
  const u16* clsWB = clsWT + b*CDIM*NPAD;
  const float* mpB = mp + ((size_t)b << 14) + p0;
  const float* rzB = rzp + ((size_t)b << 14) + p0;
  {
    int rr = t >> 3, px8 = (t & 7)*8;
    #pragma unroll
    for (int ps = 0; ps < 3; ++ps){
      int rowi = ps*64 + rr;
      if (rowi < NPAD){
        float ev[8];
        if (rowi < NCLS){
          u16x8 v = *(const u16x8*)&Sb[(size_t)rowi*HW + p0 + px8];
          #pragma unroll
          for (int j = 0; j < 8; ++j) ev[j] = __expf(h2f(v[j]) - mpB[px8 + j]);
        } else {
          #pragma unroll
          for (int j = 0; j < 8; ++j) ev[j] = 0.f;
        }
        #pragma unroll
        for (int j = 0; j < 8; ++j) E[(px8 + j)*W_STRIDE + rowi] = f2h(ev[j]);
      }
    }
  }
  __syncthreads();
  int lane = t & 63, wv = t >> 6;
  int l15 = lane & 15, lk = (lane >> 4) & 3;
  int cstrip = wv*32;
  const u16* base0 = &clsWB[(cstrip + l15)*NPAD];
  const u16* base1 = &clsWB[(cstrip + 16 + l15)*NPAD];
  f32x4 acc[2][4];
  #pragma unroll
  for (int cf = 0; cf < 2; ++cf)
    #pragma unroll
    for (int pf = 0; pf < 4; ++pf) acc[cf][pf] = (f32x4){0.f,0.f,0.f,0.f};
  f16x8 a0v[2], a1v[2];
  a0v[0] = *(const f16x8*)&base0[lk*8];
  a1v[0] = *(const f16x8*)&base1[lk*8];
  #pragma unroll
  for (int kb = 0; kb < 5; ++kb){
    int cur = kb & 1;
    if (kb < 4){
      a0v[cur^1] = *(const f16x8*)&base0[(kb+1)*32 + lk*8];
      a1v[cur^1] = *(const f16x8*)&base1[(kb+1)*32 + lk*8];
    }
    int ko = kb*32 + lk*8;
    #pragma unroll
    for (int pf = 0; pf < 4; ++pf){
      f16x8 bb = *(const f16x8*)&E[(pf*16 + l15)*W_STRIDE + ko];
      acc[0][pf] = MFMA16F(a0v[cur], bb, acc[0][pf], 0, 0, 0);
      acc[1][pf] = MFMA16F(a1v[cur], bb, acc[1][pf], 0, 0, 0);
    }
  }
  const float* featB = feat + (size_t)b*CDIM*HW;
  #pragma unroll
  for (int cf = 0; cf < 2; ++cf){
    #pragma unroll
    for (int r = 0; r < 4; ++r){
      int c = cstrip + cf*16 + lk*4 + r;
      const float* fr = featB + (size_t)c*HW + p0;
      float* ob = out1 + (size_t)(b*CDIM + c)*HW + p0;
      #pragma unroll
      for (int pf = 0; pf < 4; ++pf){
        int pp = pf*16 + l15;
        ob[pp] = acc[cf][pf][r]*rzB[pp] + fr[pp];
      }
    }
  }
}

// ---------------- kOut0: part[c][n] = sum_p featF16[c][p] * exp(S - m_g[n])  (512 px/block)
__global__ __launch_bounds__(512) void kOut0(const u16* __restrict__ Sg, const float* __restrict__ feat,
                                             const float* __restrict__ mg, u16* __restrict__ part){
  extern __shared__ char sm[];
  u16* Ep = (u16*)sm;                        // [NPAD][EP_STRIDE]
  u16* fN = (u16*)(sm + NPAD*EP_STRIDE*2);   // [CDIM][FN_STRIDE]
  int b = blockIdx.x & 7, pr = blockIdx.x >> 3, t = threadIdx.x;
  const u16* Sb = Sg + (size_t)b*NPAD*HW;
  const float* featB = feat + (size_t)b*CDIM*HW;
  const float* mgB = mg + b*NPAD;
  int lane = t & 63, wv = t >> 6;
  int l15 = lane & 15, lk = (lane >> 4) & 3;
  int cstrip = wv*32;
  int rr = t >> 3, px8 = (t & 7)*8;
  f32x4 acc[2][10];
  #pragma unroll
  for (int cf = 0; cf < 2; ++cf)
    #pragma unroll
    for (int nf = 0; nf < 10; ++nf) acc[cf][nf] = (f32x4){0.f,0.f,0.f,0.f};
  for (int ck = 0; ck < 8; ++ck){
    int p0 = pr*512 + ck*64;
    #pragma unroll
    for (int ps = 0; ps < 3; ++ps){
      int rowi = ps*64 + rr;
      if (rowi < NPAD){
        u16x8 v = *(const u16x8*)&Sb[(size_t)rowi*HW + p0 + px8];
        float m = mgB[rowi];
        u16x8 o;
        #pragma unroll
        for (int j = 0; j < 8; ++j) o[j] = f2h(__expf(h2f(v[j]) - m));
        *(u16x8*)&Ep[rowi*EP_STRIDE + px8] = o;
      }
    }
    #pragma unroll
    for (int ps = 0; ps < 4; ++ps){
      int c = ps*64 + rr;
      const float* g = featB + (size_t)c*HW + p0 + px8;
      f32x4 v0 = *(const f32x4*)&g[0];
      f32x4 v1 = *(const f32x4*)&g[4];
      u16x8 o = {f2h(v0[0]), f2h(v0[1]), f2h(v0[2]), f2h(v0[3]),
                 f2h(v1[0]), f2h(v1[1]), f2h(v1[2]), f2h(v1[3])};
      *(u16x8*)&fN[c*FN_STRIDE + px8] = o;
    }
    __syncthreads();
    #pragma unroll
    for (int kb = 0; kb < 2; ++kb){
      int ko = kb*32 + lk*8;
      f16x8 a0 = *(const f16x8*)&fN[(cstrip + l15)*FN_STRIDE + ko];
      f16x8 a1 = *(const f16x8*)&fN[(cstrip + 16 + l15)*FN_STRIDE + ko];
      #pragma unroll
      for (int nf = 0; nf < 10; ++nf){
        f16x8 bb = *(const f16x8*)&Ep[(nf*16 + l15)*EP_STRIDE + ko];
        acc[0][nf] = MFMA16F(a0, bb, acc[0][nf], 0, 0, 0);
        acc[1][nf] = MFMA16F(a1, bb, acc[1][nf], 0, 0, 0);
      }
    }
    __syncthreads();
  }
  #pragma unroll
  for (int cf = 0; cf < 2; ++cf){
    #pragma unroll
    for (int nf = 0; nf < 10; ++nf){
      #pragma unroll
      for (int r = 0; r < 4; ++r){
        int c = cstrip + cf*16 + lk*4 + r;
        int n = nf*16 + l15;
        part[((size_t)(b*32 + pr)*CDIM + c)*NPAD + n] = f2h(acc[cf][nf][r]);
      }
    }
  }
}

// ---------------- k4a: streaming reduce of part over 32 chunks, fold rZ -> combT[b][n][c] f16
__global__ __launch_bounds__(256) void k4a(const u16* __restrict__ part, const float* __restrict__ rz,
                                           u16* __restrict__ combT){
  int b = blockIdx.x / 20, sub = blockIdx.x % 20, t = threadIdx.x;
  int idx8 = (sub*256 + t)*8;          // flat (c*160+n), 8 contiguous n
  int c = idx8 / NPAD, n0 = idx8 % NPAD;
  const u16* base = part + (size_t)(b*32)*CDIM*NPAD + idx8;
  float a[8];
  #pragma unroll
  for (int j = 0; j < 8; ++j) a[j] = 0.f;
  for (int s = 0; s < 32; ++s){
    u16x8 v = *(const u16x8*)&base[(size_t)s*CDIM*NPAD];
    #pragma unroll
    for (int j = 0; j < 8; ++j) a[j] += h2f(v[j]);
  }
  const float* rzB = rz + b*NPAD + n0;
  #pragma unroll
  for (int j = 0; j < 8; ++j){
    combT[((size_t)(b*NPAD) + n0 + j)*CDIM + c] = f2h(a[j] * rzB[j]);
  }
}

// ---------------- k4b: out0[n][c] = cls + combT[n][:] @ WcF[c][:]  (MFMA, 80 n-rows/block)
__global__ __launch_bounds__(512) void k4b(const u16* __restrict__ combT, const u16* __restrict__ WcF,
                                           const float* __restrict__ cls, float* __restrict__ out0){
  extern __shared__ char sm[];
  u16* A = (u16*)sm;   // [80][CT_STRIDE]
  int b = blockIdx.x >> 1, nb = blockIdx.x & 1, t = threadIdx.x;
  const u16* cb = combT + (size_t)(b*NPAD + nb*80)*CDIM;
  #pragma unroll
  for (int it = 0; it < 10; ++it){
    int idx8 = (it*512 + t)*8;
    if (idx8 < 80*256){
      int row = idx8 >> 8, k0 = idx8 & 255;
      u16x8 v = *(const u16x8*)&cb[idx8];
      *(u16x8*)&A[row*CT_STRIDE + k0] = v;
    }
  }
  __syncthreads();
  int lane = t & 63, wv = t >> 6;
  int l15 = lane & 15, lk = (lane >> 4) & 3;
  int cstrip = wv*32;
  f32x4 acc[5][2];
  #pragma unroll
  for (int f = 0; f < 5; ++f)
    #pragma unroll
    for (int ct = 0; ct < 2; ++ct) acc[f][ct] = (f32x4){0.f,0.f,0.f,0.f};
  #pragma unroll
  for (int kb = 0; kb < 8; ++kb){
    int ko = kb*32 + lk*8;
    f16x8 b0 = *(const f16x8*)&WcF[(cstrip + l15)*CDIM + ko];
    f16x8 b1 = *(const f16x8*)&WcF[(cstrip + 16 + l15)*CDIM + ko];
    #pragma unroll
    for (int f = 0; f < 5; ++f){
      f16x8 af = *(const f16x8*)&A[(f*16 + l15)*CT_STRIDE + ko];
      acc[f][0] = MFMA16F(af, b0, acc[f][0], 0, 0, 0);
      acc[f][1] = MFMA16F(af, b1, acc[f][1], 0, 0, 0);
    }
  }
  #pragma unroll
  for (int f = 0; f < 5; ++f){
    #pragma unroll
    for (int r = 0; r < 4; ++r){
      int n = nb*80 + f*16 + lk*4 + r;
      if (n < NCLS){
        #pragma unroll
        for (int ct = 0; ct < 2; ++ct){
          int c = cstrip + ct*16 + l15;
          out0[(size_t)(b*NCLS + n)*CDIM + c] = cls[(size_t)(b*NCLS + n)*CDIM + c] + acc[f][ct][r];
        }
      }
    }
  }
}

extern "C" void kernel_launch(void* const* d_in, const int* in_sizes, int n_in,
                              void* d_out, int out_size, void* d_ws, size_t ws_size,
                              hipStream_t stream){
  (void)in_sizes; (void)n_in; (void)out_size; (void)ws_size;
  const float* cls  = (const float*)d_in[0];   // [8][150][256]
  const float* feat = (const float*)d_in[1];   // [8][256][16384]
  const float* Wc   = (const float*)d_in[2];   // [256][256]
  const float* Wf   = (const float*)d_in[3];   // [256][256]
  float* out0 = (float*)d_out;                 // [8][150][256]
  float* out1 = out0 + 8*NCLS*CDIM;            // [8][256][16384]
  char* ws = (char*)d_ws;
  u16*   clsF   = (u16*)(ws + WS_CLSF);
  u16*   clsWT  = (u16*)(ws + WS_CLSWT);
  float* mpv    = (float*)(ws + WS_MP);
  float* rzpv   = (float*)(ws + WS_RZP);
  float* mgv    = (float*)(ws + WS_MG);
  float* rzv    = (float*)(ws + WS_RZ);
  u16*   WcFv   = (u16*)(ws + WS_WCF);
  u16*   combTv = (u16*)(ws + WS_COMBT);
  float* rowPv  = (float*)(ws + WS_ROWP);
  u16*   partv  = (u16*)(ws + WS_PART);
  u16*   Sgp    = (u16*)(ws + WS_S);

  k0   <<<8*NPAD, 256, 0, stream>>>(cls, Wf, clsF, clsWT);
  kW   <<<32, 512, 0, stream>>>(Wc, WcFv);
  kS2  <<<2048, 512, S2_LDS, stream>>>(feat, clsF, Sgp, mpv, rzpv, rowPv);
  kComb<<<80, 256, 0, stream>>>(rowPv, mgv, rzv);
  kOut1<<<2048, 512, 64*W_STRIDE*2, stream>>>(Sgp, clsWT, mpv, rzpv, feat, out1);
  kOut0<<<256, 512, (NPAD*EP_STRIDE + CDIM*FN_STRIDE)*2, stream>>>(Sgp, feat, mgv, partv);
  k4a  <<<160, 256, 0, stream>>>(partv, rzv, combTv);
  k4b  <<<16, 512, 80*CT_STRIDE*2, stream>>>(combTv, WcFv, cls, out0);
}